// Round 1
// baseline (827.419 us; speedup 1.0000x reference)
//
#include <hip/hip_runtime.h>
#include <math.h>

#define BATCH 16
#define TOPN 4
#define OUTS 224
#define PADW 224
#define IM 448
#define HP 896
#define NA 1614
#define IC1 2048
#define C128 128

// d_out float offsets
#define N_PART (BATCH*TOPN*3*OUTS*OUTS)       // 9,633,792
#define OFF_TOPIDX  (N_PART)
#define OFF_TOPPROB (N_PART + BATCH*TOPN)
#define OFF_SCORE   (N_PART + 2*BATCH*TOPN)

// ws float offsets
#define WS_D1 0                                // [16][128][196] pre-ReLU
#define WS_D2 (BATCH*C128*196)                 // [16][128][49]  post-ReLU
#define WS_D3 (WS_D2 + BATCH*C128*49)          // [16][128][16]  post-ReLU
#define WS_IDX (WS_D3 + BATCH*C128*16)         // 64 ints

// ---------------- init d1 with bias ----------------
__global__ void k_init_d1(float* __restrict__ d1, const float* __restrict__ b1) {
    int i = blockIdx.x * 256 + threadIdx.x;
    if (i < BATCH * C128 * 196) d1[i] = b1[(i / 196) & 127];
}

// ---------------- conv1: 2048->128, 3x3 pad1, 14x14, split-K atomic ----------------
// grid: (64, 16)  blockIdx.x = b*4 + ocg(32 oc), blockIdx.y = kg (128 ic)
// block: 128 threads = 32 pxT x 4 ocT (8 oc each); 7 px per pxT
__global__ __launch_bounds__(128) void k_conv1(const float* __restrict__ rpn,
                                               const float* __restrict__ w1,
                                               float* __restrict__ d1) {
    __shared__ float in_s[16 * 256];   // [ic_s][y+1 (16)][x+1 (16)] zero-padded halo
    __shared__ float w_s[32 * 144];    // [oc_l][ic_s*9 + tap]
    const int tid = threadIdx.x;
    const int b = blockIdx.x >> 2, ocg = blockIdx.x & 3, kg = blockIdx.y;
    const int oc0 = ocg * 32, ic0 = kg * 128;
    const int pxT = tid & 31, ocT = tid >> 5;

    int py[7], pxx[7];
    bool act[7];
#pragma unroll
    for (int jj = 0; jj < 7; ++jj) {
        int p = pxT + 32 * jj;
        act[jj] = (p < 196);
        int pc = act[jj] ? p : 0;
        py[jj] = pc / 14; pxx[jj] = pc % 14;
    }
    float acc[8][7];
#pragma unroll
    for (int o = 0; o < 8; ++o)
#pragma unroll
        for (int jj = 0; jj < 7; ++jj) acc[o][jj] = 0.f;

    // zero LDS once (halo stays zero forever)
    for (int k = tid; k < 16 * 256; k += 128) in_s[k] = 0.f;
    __syncthreads();

    for (int ics = 0; ics < 128; ics += 16) {
        // fill interior + weights
        for (int k = tid; k < 16 * 196; k += 128) {
            int ic_s = k / 196, p = k % 196;
            int y = p / 14, x = p % 14;
            in_s[ic_s * 256 + (y + 1) * 16 + (x + 1)] =
                rpn[(size_t)(b * IC1 + ic0 + ics + ic_s) * 196 + p];
        }
        for (int k = tid; k < 32 * 144; k += 128) {
            int oc_l = k / 144, r = k % 144;
            int ic_s = r / 9, tap = r % 9;
            w_s[k] = w1[(size_t)(oc0 + oc_l) * IC1 * 9 + (size_t)(ic0 + ics + ic_s) * 9 + tap];
        }
        __syncthreads();

        for (int ic_s = 0; ic_s < 16; ++ic_s) {
#pragma unroll
            for (int ky = 0; ky < 3; ++ky) {
                float iv[7][3];
#pragma unroll
                for (int jj = 0; jj < 7; ++jj) {
                    int base = ic_s * 256 + (py[jj] + ky) * 16 + pxx[jj];
                    iv[jj][0] = in_s[base];
                    iv[jj][1] = in_s[base + 1];
                    iv[jj][2] = in_s[base + 2];
                }
#pragma unroll
                for (int o = 0; o < 8; ++o) {
                    int wb = (ocT * 8 + o) * 144 + ic_s * 9 + ky * 3;
                    float w0 = w_s[wb], w1v = w_s[wb + 1], w2v = w_s[wb + 2];
#pragma unroll
                    for (int jj = 0; jj < 7; ++jj)
                        acc[o][jj] += w0 * iv[jj][0] + w1v * iv[jj][1] + w2v * iv[jj][2];
                }
            }
        }
        __syncthreads();   // before next fill overwrites
    }

#pragma unroll
    for (int o = 0; o < 8; ++o)
#pragma unroll
        for (int jj = 0; jj < 7; ++jj)
            if (act[jj])
                atomicAdd(&d1[(size_t)(b * C128 + oc0 + ocT * 8 + o) * 196 + pxT + 32 * jj],
                          acc[o][jj]);
}

// ---------------- conv2: 128->128, 3x3 s2 pad1, 14->7, ReLU(in) & ReLU(out) ----------------
__global__ void k_conv2(const float* __restrict__ d1, const float* __restrict__ w2,
                        const float* __restrict__ b2, float* __restrict__ d2) {
    int i = blockIdx.x * 256 + threadIdx.x;
    if (i >= BATCH * C128 * 49) return;
    int px = i % 49, oc = (i / 49) & 127, b = i / (49 * 128);
    int oy = px / 7, ox = px % 7;
    float s = b2[oc];
    const float* wp = w2 + (size_t)oc * 128 * 9;
    const float* ip = d1 + (size_t)b * 128 * 196;
    for (int ic = 0; ic < 128; ++ic) {
#pragma unroll
        for (int ky = 0; ky < 3; ++ky) {
            int y = 2 * oy + ky - 1;
            if (y < 0 || y >= 14) continue;
#pragma unroll
            for (int kx = 0; kx < 3; ++kx) {
                int x = 2 * ox + kx - 1;
                if (x < 0 || x >= 14) continue;
                s += wp[ic * 9 + ky * 3 + kx] * fmaxf(ip[ic * 196 + y * 14 + x], 0.f);
            }
        }
    }
    d2[i] = fmaxf(s, 0.f);
}

// ---------------- conv3: 128->128, 3x3 s2 pad1, 7->4, input already ReLU'd ----------------
__global__ void k_conv3(const float* __restrict__ d2, const float* __restrict__ w3,
                        const float* __restrict__ b3, float* __restrict__ d3) {
    int i = blockIdx.x * 256 + threadIdx.x;
    if (i >= BATCH * C128 * 16) return;
    int px = i & 15, oc = (i / 16) & 127, b = i / (16 * 128);
    int oy = px / 4, ox = px % 4;
    float s = b3[oc];
    const float* wp = w3 + (size_t)oc * 128 * 9;
    const float* ip = d2 + (size_t)b * 128 * 49;
    for (int ic = 0; ic < 128; ++ic) {
#pragma unroll
        for (int ky = 0; ky < 3; ++ky) {
            int y = 2 * oy + ky - 1;
            if (y < 0 || y >= 7) continue;
#pragma unroll
            for (int kx = 0; kx < 3; ++kx) {
                int x = 2 * ox + kx - 1;
                if (x < 0 || x >= 7) continue;
                s += wp[ic * 9 + ky * 3 + kx] * ip[ic * 49 + y * 7 + x];
            }
        }
    }
    d3[i] = fmaxf(s, 0.f);
}

// ---------------- tidy 1x1 convs -> concatenated scores [B,1614] ----------------
__global__ void k_tidy(const float* __restrict__ d1, const float* __restrict__ d2,
                       const float* __restrict__ d3,
                       const float* __restrict__ wt1, const float* __restrict__ bt1,
                       const float* __restrict__ wt2, const float* __restrict__ bt2,
                       const float* __restrict__ wt3, const float* __restrict__ bt3,
                       float* __restrict__ score) {
    int i = blockIdx.x * 256 + threadIdx.x;
    if (i >= BATCH * NA) return;
    int b = i / NA, j = i % NA;
    float s;
    if (j < 1176) {
        int c = j / 196, px = j % 196;
        s = bt1[c];
        const float* ip = d1 + (size_t)b * 128 * 196 + px;
        for (int ic = 0; ic < 128; ++ic) s += wt1[c * 128 + ic] * fmaxf(ip[ic * 196], 0.f);
    } else if (j < 1470) {
        int c = (j - 1176) / 49, px = (j - 1176) % 49;
        s = bt2[c];
        const float* ip = d2 + (size_t)b * 128 * 49 + px;
        for (int ic = 0; ic < 128; ++ic) s += wt2[c * 128 + ic] * ip[ic * 49];
    } else {
        int c = (j - 1470) / 16, px = (j - 1470) % 16;
        s = bt3[c];
        const float* ip = d3 + (size_t)b * 128 * 16 + px;
        for (int ic = 0; ic < 128; ++ic) s += wt3[c * 128 + ic] * ip[ic * 16];
    }
    score[b * NA + j] = s;
}

// ---------------- greedy hard-NMS, top-4, per batch ----------------
__global__ __launch_bounds__(256) void k_nms(const float* __restrict__ score,
                                             const int* __restrict__ anchors,
                                             float* __restrict__ out_idx,
                                             float* __restrict__ out_prob,
                                             int* __restrict__ idx_ws) {
    __shared__ float s[NA], y0s[NA], x0s[NA], y1s[NA], x1s[NA], ar[NA];
    __shared__ float rv[256];
    __shared__ int ri[256];
    int b = blockIdx.x, tid = threadIdx.x;
    for (int j = tid; j < NA; j += 256) {
        s[j] = score[b * NA + j];
        float a0 = (float)anchors[j * 4], a1 = (float)anchors[j * 4 + 1];
        float a2 = (float)anchors[j * 4 + 2], a3 = (float)anchors[j * 4 + 3];
        y0s[j] = a0; x0s[j] = a1; y1s[j] = a2; x1s[j] = a3;
        ar[j] = (a2 - a0) * (a3 - a1);
    }
    __syncthreads();
    for (int it = 0; it < TOPN; ++it) {
        float bv = -INFINITY; int bi = NA;
        for (int j = tid; j < NA; j += 256) {
            float v = s[j];
            if (v > bv || (v == bv && j < bi)) { bv = v; bi = j; }
        }
        rv[tid] = bv; ri[tid] = bi;
        __syncthreads();
        for (int off = 128; off > 0; off >>= 1) {
            if (tid < off) {
                float ov = rv[tid + off]; int oi = ri[tid + off];
                if (ov > rv[tid] || (ov == rv[tid] && oi < ri[tid])) { rv[tid] = ov; ri[tid] = oi; }
            }
            __syncthreads();
        }
        int K = ri[0]; float V = rv[0];
        if (tid == 0) {
            out_idx[b * TOPN + it] = (float)K;   // harness reads fp32
            out_prob[b * TOPN + it] = V;          // original score of pick
            idx_ws[b * TOPN + it] = K;
        }
        float ky0 = y0s[K], kx0 = x0s[K], ky1 = y1s[K], kx1 = x1s[K], ka = ar[K];
        for (int j = tid; j < NA; j += 256) {
            float iy = fmaxf(fminf(y1s[j], ky1) - fmaxf(y0s[j], ky0), 0.f);
            float ix = fmaxf(fminf(x1s[j], kx1) - fmaxf(x0s[j], kx0), 0.f);
            float inter = iy * ix;
            float iou = inter / (ar[j] + ka - inter);
            if (iou >= 0.25f) s[j] = -INFINITY;
        }
        __syncthreads();
    }
}

// ---------------- bilinear crop-resize (align_corners=True, zero-padded source) ----------------
// grid: 64*224 blocks (crop, row), 256 threads (col; j<224 active)
__global__ __launch_bounds__(256) void k_crop(const float* __restrict__ x,
                                              const int* __restrict__ anchors,
                                              const int* __restrict__ idx_ws,
                                              float* __restrict__ out) {
    int blk = blockIdx.x;
    int crop = blk / OUTS;
    int i = blk % OUTS;
    int j = threadIdx.x;
    if (j >= OUTS) return;
    int b = crop >> 2;
    int a = idx_ws[crop];
    int y0 = anchors[a * 4], x0 = anchors[a * 4 + 1];
    int y1 = anchors[a * 4 + 2], x1 = anchors[a * 4 + 3];

    float ti = (float)i / 223.f;
    float ys = (float)y0 + ti * (float)(y1 - y0 - 1);
    int yi0 = (int)ys;                       // ys >= 0 -> trunc == floor
    int yi1 = min(yi0 + 1, HP - 1);
    float wy = ys - (float)yi0;

    float tj = (float)j / 223.f;
    float xs = (float)x0 + tj * (float)(x1 - x0 - 1);
    int xi0 = (int)xs;
    int xi1 = min(xi0 + 1, HP - 1);
    float wx = xs - (float)xi0;

    int ry0 = yi0 - PADW, ry1 = yi1 - PADW, rx0 = xi0 - PADW, rx1 = xi1 - PADW;
    bool vy0 = (ry0 >= 0) && (ry0 < IM), vy1 = (ry1 >= 0) && (ry1 < IM);
    bool vx0 = (rx0 >= 0) && (rx0 < IM), vx1 = (rx1 >= 0) && (rx1 < IM);

    float w00 = (1.f - wy) * (1.f - wx), w01 = (1.f - wy) * wx;
    float w10 = wy * (1.f - wx), w11 = wy * wx;

#pragma unroll
    for (int c = 0; c < 3; ++c) {
        const float* xp = x + (size_t)(b * 3 + c) * IM * IM;
        float g00 = (vy0 && vx0) ? xp[ry0 * IM + rx0] : 0.f;
        float g01 = (vy0 && vx1) ? xp[ry0 * IM + rx1] : 0.f;
        float g10 = (vy1 && vx0) ? xp[ry1 * IM + rx0] : 0.f;
        float g11 = (vy1 && vx1) ? xp[ry1 * IM + rx1] : 0.f;
        out[(size_t)(crop * 3 + c) * OUTS * OUTS + i * OUTS + j] =
            g00 * w00 + g01 * w01 + g10 * w10 + g11 * w11;
    }
}

extern "C" void kernel_launch(void* const* d_in, const int* in_sizes, int n_in,
                              void* d_out, int out_size, void* d_ws, size_t ws_size,
                              hipStream_t stream) {
    (void)in_sizes; (void)n_in; (void)out_size; (void)ws_size;
    const float* x    = (const float*)d_in[0];
    const float* rpn  = (const float*)d_in[1];
    const float* w1   = (const float*)d_in[2];
    const float* b1   = (const float*)d_in[3];
    const float* w2   = (const float*)d_in[4];
    const float* b2   = (const float*)d_in[5];
    const float* w3   = (const float*)d_in[6];
    const float* b3   = (const float*)d_in[7];
    const float* wt1  = (const float*)d_in[8];
    const float* bt1  = (const float*)d_in[9];
    const float* wt2  = (const float*)d_in[10];
    const float* bt2  = (const float*)d_in[11];
    const float* wt3  = (const float*)d_in[12];
    const float* bt3  = (const float*)d_in[13];
    const int*   anc  = (const int*)d_in[14];

    float* out = (float*)d_out;
    float* ws  = (float*)d_ws;
    float* d1  = ws + WS_D1;
    float* d2  = ws + WS_D2;
    float* d3  = ws + WS_D3;
    int*   idxw = (int*)(ws + WS_IDX);

    k_init_d1<<<(BATCH * C128 * 196 + 255) / 256, 256, 0, stream>>>(d1, b1);
    k_conv1<<<dim3(64, 16), 128, 0, stream>>>(rpn, w1, d1);
    k_conv2<<<(BATCH * C128 * 49 + 255) / 256, 256, 0, stream>>>(d1, w2, b2, d2);
    k_conv3<<<(BATCH * C128 * 16 + 255) / 256, 256, 0, stream>>>(d2, w3, b3, d3);
    k_tidy<<<(BATCH * NA + 255) / 256, 256, 0, stream>>>(d1, d2, d3, wt1, bt1, wt2, bt2,
                                                         wt3, bt3, out + OFF_SCORE);
    k_nms<<<BATCH, 256, 0, stream>>>(out + OFF_SCORE, anc, out + OFF_TOPIDX,
                                     out + OFF_TOPPROB, idxw);
    k_crop<<<BATCH * TOPN * OUTS, 256, 0, stream>>>(x, anc, idxw, out);
}

// Round 2
// 595.806 us; speedup vs baseline: 1.3887x; 1.3887x over previous
//
#include <hip/hip_runtime.h>
#include <math.h>

#define BATCH 16
#define TOPN 4
#define OUTS 224
#define PADW 224
#define IM 448
#define HP 896
#define NA 1614
#define IC1 2048
#define C128 128

// d_out float offsets
#define N_PART (BATCH*TOPN*3*OUTS*OUTS)       // 9,633,792
#define OFF_TOPIDX  (N_PART)
#define OFF_TOPPROB (N_PART + BATCH*TOPN)
#define OFF_SCORE   (N_PART + 2*BATCH*TOPN)

// ws float offsets
#define WS_D1 0                                // [16][128][196] pre-ReLU
#define WS_D2 (BATCH*C128*196)                 // [16][128][49]  post-ReLU
#define WS_D3 (WS_D2 + BATCH*C128*49)          // [16][128][16]  post-ReLU
#define WS_IDX (WS_D3 + BATCH*C128*16)         // 64 ints
#define WS_WT  (WS_IDX + 64)                   // then 2x [9][2048][128] ushort (bf16 hi, lo)
#define NWT (9*2048*128)

typedef __attribute__((ext_vector_type(8))) short frag8;     // 8 bf16 (4 VGPRs)
typedef __attribute__((ext_vector_type(16))) float acc16;    // 16 fp32 acc

__device__ __forceinline__ unsigned short f2bf(float f) {
    unsigned int u = __float_as_uint(f);
    u = (u + 0x7fffu + ((u >> 16) & 1u)) >> 16;   // RNE
    return (unsigned short)u;
}
__device__ __forceinline__ float bf2f(unsigned short h) {
    return __uint_as_float(((unsigned int)h) << 16);
}

// ---------------- init d1 with bias ----------------
__global__ void k_init_d1(float* __restrict__ d1, const float* __restrict__ b1) {
    int i = blockIdx.x * 256 + threadIdx.x;
    if (i < BATCH * C128 * 196) d1[i] = b1[(i / 196) & 127];
}

// ---------------- weight repack: w1[oc][ic][tap] fp32 -> wt[tap][ic][oc] bf16 hi/lo ----------------
// grid 1024 blocks: each handles 2 ic x 9 taps x 128 oc, LDS tile transpose
__global__ __launch_bounds__(256) void k_wprep(const float* __restrict__ w1,
                                               unsigned short* __restrict__ wt_hi,
                                               unsigned short* __restrict__ wt_lo) {
    __shared__ float tile[128 * 19];   // [oc][k], k = icl*9+tap (18), stride 19
    const int tid = threadIdx.x;
    const int ic0 = blockIdx.x * 2;
#pragma unroll
    for (int i = 0; i < 9; ++i) {
        int flat = tid + 256 * i;          // < 2304
        int oc = flat / 18, k = flat % 18;
        int icl = k / 9, tap = k % 9;
        tile[oc * 19 + k] = w1[(size_t)oc * (IC1 * 9) + (size_t)(ic0 + icl) * 9 + tap];
    }
    __syncthreads();
#pragma unroll
    for (int i = 0; i < 9; ++i) {
        int flat = tid + 256 * i;
        int kk = flat / 128, oc = flat % 128;
        int icl = kk / 9, tap = kk % 9;
        float v = tile[oc * 19 + kk];
        unsigned short h = f2bf(v);
        size_t gi = (size_t)(tap * IC1 + ic0 + icl) * 128 + oc;
        wt_hi[gi] = h;
        wt_lo[gi] = f2bf(v - bf2f(h));
    }
}

// ---------------- conv1 via MFMA 32x32x16 bf16, hi/lo split (3 products) ----------------
// grid 256: blockIdx.x = kg*16 + b; block 256 thr = 4 waves
// wave w: mh=w&1 (oc half of 64), nh=w>>1 (4 N-tiles of 32 px, N padded 196->256)
__global__ __launch_bounds__(256, 1) void k_conv1_mfma(const float* __restrict__ rpn,
                                                       const unsigned short* __restrict__ wt_hi,
                                                       const unsigned short* __restrict__ wt_lo,
                                                       float* __restrict__ d1) {
    // LDS: input halo image [pos 304][ic 72] (pos = (y+1)*16+(x+1); 256..303 = zero pad region)
    __shared__ unsigned short inH[304 * 72];
    __shared__ unsigned short inL[304 * 72];
    __shared__ unsigned short wHs[128 * 72];   // [oc][ic 64 (+pad)]
    __shared__ unsigned short wLs[128 * 72];

    const int tid = threadIdx.x;
    const int b = blockIdx.x & 15, kg = blockIdx.x >> 4;
    const int l = tid & 63, w = tid >> 6;
    const int ln = l & 31, q = l >> 5;
    const int mh = w & 1, nh = w >> 1;

    // zero LDS input (halo + pad region stay zero; interior overwritten per half)
    for (int i = tid; i < 304 * 72; i += 256) { inH[i] = 0; inL[i] = 0; }

    acc16 acc[2][4];
#pragma unroll
    for (int mt = 0; mt < 2; ++mt)
#pragma unroll
        for (int nt = 0; nt < 4; ++nt)
#pragma unroll
            for (int r = 0; r < 16; ++r) acc[mt][nt][r] = 0.f;

    int posb[4];
#pragma unroll
    for (int nt = 0; nt < 4; ++nt) {
        int px = (nh * 4 + nt) * 32 + ln;
        posb[nt] = (px < 196) ? ((px / 14) * 16 + (px % 14)) : 256;  // 256 -> zero region
    }
    __syncthreads();

    for (int half = 0; half < 2; ++half) {
        const int ics = kg * 128 + half * 64;
        // ---- stage input half: rpn[b][ics..ics+63][196] -> inH/inL [pos][icl]
        for (int qq = tid; qq < 3136; qq += 256) {
            int icl = qq / 49, r = qq % 49, p = r * 4;
            const float4 v = *(const float4*)&rpn[(size_t)(b * IC1 + ics + icl) * 196 + p];
            float vv[4] = {v.x, v.y, v.z, v.w};
#pragma unroll
            for (int e = 0; e < 4; ++e) {
                int px = p + e;
                int pos = (px / 14 + 1) * 16 + (px % 14 + 1);
                unsigned short h = f2bf(vv[e]);
                inH[pos * 72 + icl] = h;
                inL[pos * 72 + icl] = f2bf(vv[e] - bf2f(h));
            }
        }
        __syncthreads();

        for (int tap = 0; tap < 9; ++tap) {
            // ---- stage weights for (half, tap): wt[tap][ics..+63][128 oc] -> wHs/wLs [oc][icl]
            for (int qq = tid; qq < 2048; qq += 256) {
                int icl = qq >> 5, ocq = (qq & 31) * 4;
                size_t gi = (size_t)(tap * IC1 + ics + icl) * 128 + ocq;
                ushort4 hv = *(const ushort4*)&wt_hi[gi];
                ushort4 lv = *(const ushort4*)&wt_lo[gi];
                wHs[(ocq + 0) * 72 + icl] = hv.x; wLs[(ocq + 0) * 72 + icl] = lv.x;
                wHs[(ocq + 1) * 72 + icl] = hv.y; wLs[(ocq + 1) * 72 + icl] = lv.y;
                wHs[(ocq + 2) * 72 + icl] = hv.z; wLs[(ocq + 2) * 72 + icl] = lv.z;
                wHs[(ocq + 3) * 72 + icl] = hv.w; wLs[(ocq + 3) * 72 + icl] = lv.w;
            }
            __syncthreads();

            const int off = (tap / 3) * 16 + (tap % 3);
#pragma unroll
            for (int c = 0; c < 4; ++c) {          // 16-ic K chunks
                const int ko = c * 16 + q * 8;
                frag8 aH[2], aL[2], bH[4], bL[4];
#pragma unroll
                for (int mt = 0; mt < 2; ++mt) {
                    int oc = mh * 64 + mt * 32 + ln;
                    aH[mt] = *(const frag8*)&wHs[oc * 72 + ko];
                    aL[mt] = *(const frag8*)&wLs[oc * 72 + ko];
                }
#pragma unroll
                for (int nt = 0; nt < 4; ++nt) {
                    int pp = (posb[nt] + off) * 72 + ko;
                    bH[nt] = *(const frag8*)&inH[pp];
                    bL[nt] = *(const frag8*)&inL[pp];
                }
#pragma unroll
                for (int mt = 0; mt < 2; ++mt)
#pragma unroll
                    for (int nt = 0; nt < 4; ++nt) {
                        acc[mt][nt] = __builtin_amdgcn_mfma_f32_32x32x16_bf16(aH[mt], bH[nt], acc[mt][nt], 0, 0, 0);
                        acc[mt][nt] = __builtin_amdgcn_mfma_f32_32x32x16_bf16(aH[mt], bL[nt], acc[mt][nt], 0, 0, 0);
                        acc[mt][nt] = __builtin_amdgcn_mfma_f32_32x32x16_bf16(aL[mt], bH[nt], acc[mt][nt], 0, 0, 0);
                    }
            }
            __syncthreads();
        }
    }

    // ---- epilogue: atomic split-K accumulate into bias-initialized d1
    // C/D layout (32x32): col(n=px) = lane&31, row(m=oc) = (r&3) + 8*(r>>2) + 4*(lane>>5)
#pragma unroll
    for (int mt = 0; mt < 2; ++mt)
#pragma unroll
        for (int nt = 0; nt < 4; ++nt) {
            int px = (nh * 4 + nt) * 32 + ln;
            if (px < 196) {
#pragma unroll
                for (int r = 0; r < 16; ++r) {
                    int m = (r & 3) + 8 * (r >> 2) + 4 * q;
                    int oc = mh * 64 + mt * 32 + m;
                    atomicAdd(&d1[(size_t)(b * C128 + oc) * 196 + px], acc[mt][nt][r]);
                }
            }
        }
}

// ---------------- conv2: 128->128, 3x3 s2 pad1, 14->7, ReLU(in) & ReLU(out) ----------------
__global__ void k_conv2(const float* __restrict__ d1, const float* __restrict__ w2,
                        const float* __restrict__ b2, float* __restrict__ d2) {
    int i = blockIdx.x * 256 + threadIdx.x;
    if (i >= BATCH * C128 * 49) return;
    int px = i % 49, oc = (i / 49) & 127, b = i / (49 * 128);
    int oy = px / 7, ox = px % 7;
    float s = b2[oc];
    const float* wp = w2 + (size_t)oc * 128 * 9;
    const float* ip = d1 + (size_t)b * 128 * 196;
    for (int ic = 0; ic < 128; ++ic) {
#pragma unroll
        for (int ky = 0; ky < 3; ++ky) {
            int y = 2 * oy + ky - 1;
            if (y < 0 || y >= 14) continue;
#pragma unroll
            for (int kx = 0; kx < 3; ++kx) {
                int x = 2 * ox + kx - 1;
                if (x < 0 || x >= 14) continue;
                s += wp[ic * 9 + ky * 3 + kx] * fmaxf(ip[ic * 196 + y * 14 + x], 0.f);
            }
        }
    }
    d2[i] = fmaxf(s, 0.f);
}

// ---------------- conv3: 128->128, 3x3 s2 pad1, 7->4, input already ReLU'd ----------------
__global__ void k_conv3(const float* __restrict__ d2, const float* __restrict__ w3,
                        const float* __restrict__ b3, float* __restrict__ d3) {
    int i = blockIdx.x * 256 + threadIdx.x;
    if (i >= BATCH * C128 * 16) return;
    int px = i & 15, oc = (i / 16) & 127, b = i / (16 * 128);
    int oy = px / 4, ox = px % 4;
    float s = b3[oc];
    const float* wp = w3 + (size_t)oc * 128 * 9;
    const float* ip = d2 + (size_t)b * 128 * 49;
    for (int ic = 0; ic < 128; ++ic) {
#pragma unroll
        for (int ky = 0; ky < 3; ++ky) {
            int y = 2 * oy + ky - 1;
            if (y < 0 || y >= 7) continue;
#pragma unroll
            for (int kx = 0; kx < 3; ++kx) {
                int x = 2 * ox + kx - 1;
                if (x < 0 || x >= 7) continue;
                s += wp[ic * 9 + ky * 3 + kx] * ip[ic * 49 + y * 7 + x];
            }
        }
    }
    d3[i] = fmaxf(s, 0.f);
}

// ---------------- tidy 1x1 convs -> concatenated scores [B,1614] ----------------
__global__ void k_tidy(const float* __restrict__ d1, const float* __restrict__ d2,
                       const float* __restrict__ d3,
                       const float* __restrict__ wt1, const float* __restrict__ bt1,
                       const float* __restrict__ wt2, const float* __restrict__ bt2,
                       const float* __restrict__ wt3, const float* __restrict__ bt3,
                       float* __restrict__ score) {
    int i = blockIdx.x * 256 + threadIdx.x;
    if (i >= BATCH * NA) return;
    int b = i / NA, j = i % NA;
    float s;
    if (j < 1176) {
        int c = j / 196, px = j % 196;
        s = bt1[c];
        const float* ip = d1 + (size_t)b * 128 * 196 + px;
        for (int ic = 0; ic < 128; ++ic) s += wt1[c * 128 + ic] * fmaxf(ip[ic * 196], 0.f);
    } else if (j < 1470) {
        int c = (j - 1176) / 49, px = (j - 1176) % 49;
        s = bt2[c];
        const float* ip = d2 + (size_t)b * 128 * 49 + px;
        for (int ic = 0; ic < 128; ++ic) s += wt2[c * 128 + ic] * ip[ic * 49];
    } else {
        int c = (j - 1470) / 16, px = (j - 1470) % 16;
        s = bt3[c];
        const float* ip = d3 + (size_t)b * 128 * 16 + px;
        for (int ic = 0; ic < 128; ++ic) s += wt3[c * 128 + ic] * ip[ic * 16];
    }
    score[b * NA + j] = s;
}

// ---------------- greedy hard-NMS, top-4, per batch ----------------
__global__ __launch_bounds__(256) void k_nms(const float* __restrict__ score,
                                             const int* __restrict__ anchors,
                                             float* __restrict__ out_idx,
                                             float* __restrict__ out_prob,
                                             int* __restrict__ idx_ws) {
    __shared__ float s[NA], y0s[NA], x0s[NA], y1s[NA], x1s[NA], ar[NA];
    __shared__ float rv[256];
    __shared__ int ri[256];
    int b = blockIdx.x, tid = threadIdx.x;
    for (int j = tid; j < NA; j += 256) {
        s[j] = score[b * NA + j];
        float a0 = (float)anchors[j * 4], a1 = (float)anchors[j * 4 + 1];
        float a2 = (float)anchors[j * 4 + 2], a3 = (float)anchors[j * 4 + 3];
        y0s[j] = a0; x0s[j] = a1; y1s[j] = a2; x1s[j] = a3;
        ar[j] = (a2 - a0) * (a3 - a1);
    }
    __syncthreads();
    for (int it = 0; it < TOPN; ++it) {
        float bv = -INFINITY; int bi = NA;
        for (int j = tid; j < NA; j += 256) {
            float v = s[j];
            if (v > bv || (v == bv && j < bi)) { bv = v; bi = j; }
        }
        rv[tid] = bv; ri[tid] = bi;
        __syncthreads();
        for (int off = 128; off > 0; off >>= 1) {
            if (tid < off) {
                float ov = rv[tid + off]; int oi = ri[tid + off];
                if (ov > rv[tid] || (ov == rv[tid] && oi < ri[tid])) { rv[tid] = ov; ri[tid] = oi; }
            }
            __syncthreads();
        }
        int K = ri[0]; float V = rv[0];
        if (tid == 0) {
            out_idx[b * TOPN + it] = (float)K;   // harness reads fp32
            out_prob[b * TOPN + it] = V;
            idx_ws[b * TOPN + it] = K;
        }
        float ky0 = y0s[K], kx0 = x0s[K], ky1 = y1s[K], kx1 = x1s[K], ka = ar[K];
        for (int j = tid; j < NA; j += 256) {
            float iy = fmaxf(fminf(y1s[j], ky1) - fmaxf(y0s[j], ky0), 0.f);
            float ix = fmaxf(fminf(x1s[j], kx1) - fmaxf(x0s[j], kx0), 0.f);
            float inter = iy * ix;
            float iou = inter / (ar[j] + ka - inter);
            if (iou >= 0.25f) s[j] = -INFINITY;
        }
        __syncthreads();
    }
}

// ---------------- bilinear crop-resize (align_corners=True, zero-padded source) ----------------
__global__ __launch_bounds__(256) void k_crop(const float* __restrict__ x,
                                              const int* __restrict__ anchors,
                                              const int* __restrict__ idx_ws,
                                              float* __restrict__ out) {
    int blk = blockIdx.x;
    int crop = blk / OUTS;
    int i = blk % OUTS;
    int j = threadIdx.x;
    if (j >= OUTS) return;
    int b = crop >> 2;
    int a = idx_ws[crop];
    int y0 = anchors[a * 4], x0 = anchors[a * 4 + 1];
    int y1 = anchors[a * 4 + 2], x1 = anchors[a * 4 + 3];

    float ti = (float)i / 223.f;
    float ys = (float)y0 + ti * (float)(y1 - y0 - 1);
    int yi0 = (int)ys;
    int yi1 = min(yi0 + 1, HP - 1);
    float wy = ys - (float)yi0;

    float tj = (float)j / 223.f;
    float xs = (float)x0 + tj * (float)(x1 - x0 - 1);
    int xi0 = (int)xs;
    int xi1 = min(xi0 + 1, HP - 1);
    float wx = xs - (float)xi0;

    int ry0 = yi0 - PADW, ry1 = yi1 - PADW, rx0 = xi0 - PADW, rx1 = xi1 - PADW;
    bool vy0 = (ry0 >= 0) && (ry0 < IM), vy1 = (ry1 >= 0) && (ry1 < IM);
    bool vx0 = (rx0 >= 0) && (rx0 < IM), vx1 = (rx1 >= 0) && (rx1 < IM);

    float w00 = (1.f - wy) * (1.f - wx), w01 = (1.f - wy) * wx;
    float w10 = wy * (1.f - wx), w11 = wy * wx;

#pragma unroll
    for (int c = 0; c < 3; ++c) {
        const float* xp = x + (size_t)(b * 3 + c) * IM * IM;
        float g00 = (vy0 && vx0) ? xp[ry0 * IM + rx0] : 0.f;
        float g01 = (vy0 && vx1) ? xp[ry0 * IM + rx1] : 0.f;
        float g10 = (vy1 && vx0) ? xp[ry1 * IM + rx0] : 0.f;
        float g11 = (vy1 && vx1) ? xp[ry1 * IM + rx1] : 0.f;
        out[(size_t)(crop * 3 + c) * OUTS * OUTS + i * OUTS + j] =
            g00 * w00 + g01 * w01 + g10 * w10 + g11 * w11;
    }
}

extern "C" void kernel_launch(void* const* d_in, const int* in_sizes, int n_in,
                              void* d_out, int out_size, void* d_ws, size_t ws_size,
                              hipStream_t stream) {
    (void)in_sizes; (void)n_in; (void)out_size; (void)ws_size;
    const float* x    = (const float*)d_in[0];
    const float* rpn  = (const float*)d_in[1];
    const float* w1   = (const float*)d_in[2];
    const float* b1   = (const float*)d_in[3];
    const float* w2   = (const float*)d_in[4];
    const float* b2   = (const float*)d_in[5];
    const float* w3   = (const float*)d_in[6];
    const float* b3   = (const float*)d_in[7];
    const float* wt1  = (const float*)d_in[8];
    const float* bt1  = (const float*)d_in[9];
    const float* wt2  = (const float*)d_in[10];
    const float* bt2  = (const float*)d_in[11];
    const float* wt3  = (const float*)d_in[12];
    const float* bt3  = (const float*)d_in[13];
    const int*   anc  = (const int*)d_in[14];

    float* out = (float*)d_out;
    float* ws  = (float*)d_ws;
    float* d1  = ws + WS_D1;
    float* d2  = ws + WS_D2;
    float* d3  = ws + WS_D3;
    int*   idxw = (int*)(ws + WS_IDX);
    unsigned short* wt_hi = (unsigned short*)(ws + WS_WT);
    unsigned short* wt_lo = wt_hi + NWT;

    k_wprep<<<1024, 256, 0, stream>>>(w1, wt_hi, wt_lo);
    k_init_d1<<<(BATCH * C128 * 196 + 255) / 256, 256, 0, stream>>>(d1, b1);
    k_conv1_mfma<<<256, 256, 0, stream>>>(rpn, wt_hi, wt_lo, d1);
    k_conv2<<<(BATCH * C128 * 49 + 255) / 256, 256, 0, stream>>>(d1, w2, b2, d2);
    k_conv3<<<(BATCH * C128 * 16 + 255) / 256, 256, 0, stream>>>(d2, w3, b3, d3);
    k_tidy<<<(BATCH * NA + 255) / 256, 256, 0, stream>>>(d1, d2, d3, wt1, bt1, wt2, bt2,
                                                         wt3, bt3, out + OFF_SCORE);
    k_nms<<<BATCH, 256, 0, stream>>>(out + OFF_SCORE, anc, out + OFF_TOPIDX,
                                     out + OFF_TOPPROB, idxw);
    k_crop<<<BATCH * TOPN * OUTS, 256, 0, stream>>>(x, anc, idxw, out);
}

// Round 3
// 490.544 us; speedup vs baseline: 1.6867x; 1.2146x over previous
//
#include <hip/hip_runtime.h>
#include <math.h>

#define BATCH 16
#define TOPN 4
#define OUTS 224
#define PADW 224
#define IM 448
#define HP 896
#define NA 1614
#define IC1 2048
#define C128 128

// d_out float offsets
#define N_PART (BATCH*TOPN*3*OUTS*OUTS)       // 9,633,792
#define OFF_TOPIDX  (N_PART)
#define OFF_TOPPROB (N_PART + BATCH*TOPN)
#define OFF_SCORE   (N_PART + 2*BATCH*TOPN)

// ws float offsets
#define WS_D1 0                                // [16][128][196] pre-ReLU
#define WS_IDX (BATCH*C128*196)                // 64 ints
#define WS_WT  (WS_IDX + 64)                   // repacked weights (ushort)
#define NWT1 (9*2048*128)
#define NWT2 (9*128*128)

typedef __attribute__((ext_vector_type(8))) short frag8;     // 8 bf16 (4 VGPRs)
typedef __attribute__((ext_vector_type(16))) float acc16;    // 16 fp32 acc (32x32)
typedef __attribute__((ext_vector_type(4)))  float acc4;     // 4 fp32 acc (16x16)

__device__ __forceinline__ unsigned short f2bf(float f) {
    unsigned int u = __float_as_uint(f);
    u = (u + 0x7fffu + ((u >> 16) & 1u)) >> 16;   // RNE
    return (unsigned short)u;
}
__device__ __forceinline__ float bf2f(unsigned short h) {
    return __uint_as_float(((unsigned int)h) << 16);
}

// ---------------- init d1 with bias ----------------
__global__ void k_init_d1(float* __restrict__ d1, const float* __restrict__ b1) {
    int i = blockIdx.x * 256 + threadIdx.x;
    if (i < BATCH * C128 * 196) d1[i] = b1[(i / 196) & 127];
}

// ---------------- weight repack: w[oc<128][ic<IC][tap<9] fp32 -> [tap][ic][oc] bf16 hi/lo ----
// grid IC/2 blocks
__global__ __launch_bounds__(256) void k_wrepack(const float* __restrict__ w,
                                                 unsigned short* __restrict__ w_hi,
                                                 unsigned short* __restrict__ w_lo,
                                                 int IC) {
    __shared__ float tile[128 * 19];   // [oc][k], k = icl*9+tap (18), stride 19
    const int tid = threadIdx.x;
    const int ic0 = blockIdx.x * 2;
#pragma unroll
    for (int i = 0; i < 9; ++i) {
        int flat = tid + 256 * i;          // < 2304
        int oc = flat / 18, k = flat % 18;
        int icl = k / 9, tap = k % 9;
        tile[oc * 19 + k] = w[(size_t)oc * (IC * 9) + (size_t)(ic0 + icl) * 9 + tap];
    }
    __syncthreads();
#pragma unroll
    for (int i = 0; i < 9; ++i) {
        int flat = tid + 256 * i;
        int kk = flat / 128, oc = flat % 128;
        int icl = kk / 9, tap = kk % 9;
        float v = tile[oc * 19 + kk];
        unsigned short h = f2bf(v);
        size_t gi = (size_t)(tap * IC + ic0 + icl) * 128 + oc;
        w_hi[gi] = h;
        w_lo[gi] = f2bf(v - bf2f(h));
    }
}

// ---------------- conv1 via MFMA 32x32x16 bf16, hi/lo split (3 products) ----------------
__global__ __launch_bounds__(256, 1) void k_conv1_mfma(const float* __restrict__ rpn,
                                                       const unsigned short* __restrict__ wt_hi,
                                                       const unsigned short* __restrict__ wt_lo,
                                                       float* __restrict__ d1) {
    __shared__ unsigned short inH[304 * 72];
    __shared__ unsigned short inL[304 * 72];
    __shared__ unsigned short wHs[128 * 72];
    __shared__ unsigned short wLs[128 * 72];

    const int tid = threadIdx.x;
    const int b = blockIdx.x & 15, kg = blockIdx.x >> 4;
    const int l = tid & 63, w = tid >> 6;
    const int ln = l & 31, q = l >> 5;
    const int mh = w & 1, nh = w >> 1;

    for (int i = tid; i < 304 * 72; i += 256) { inH[i] = 0; inL[i] = 0; }

    acc16 acc[2][4];
#pragma unroll
    for (int mt = 0; mt < 2; ++mt)
#pragma unroll
        for (int nt = 0; nt < 4; ++nt)
#pragma unroll
            for (int r = 0; r < 16; ++r) acc[mt][nt][r] = 0.f;

    int posb[4];
#pragma unroll
    for (int nt = 0; nt < 4; ++nt) {
        int px = (nh * 4 + nt) * 32 + ln;
        posb[nt] = (px < 196) ? ((px / 14) * 16 + (px % 14)) : 256;
    }
    __syncthreads();

    for (int half = 0; half < 2; ++half) {
        const int ics = kg * 128 + half * 64;
        for (int qq = tid; qq < 3136; qq += 256) {
            int icl = qq / 49, r = qq % 49, p = r * 4;
            const float4 v = *(const float4*)&rpn[(size_t)(b * IC1 + ics + icl) * 196 + p];
            float vv[4] = {v.x, v.y, v.z, v.w};
#pragma unroll
            for (int e = 0; e < 4; ++e) {
                int px = p + e;
                int pos = (px / 14 + 1) * 16 + (px % 14 + 1);
                unsigned short h = f2bf(vv[e]);
                inH[pos * 72 + icl] = h;
                inL[pos * 72 + icl] = f2bf(vv[e] - bf2f(h));
            }
        }
        __syncthreads();

        for (int tap = 0; tap < 9; ++tap) {
            for (int qq = tid; qq < 2048; qq += 256) {
                int icl = qq >> 5, ocq = (qq & 31) * 4;
                size_t gi = (size_t)(tap * IC1 + ics + icl) * 128 + ocq;
                ushort4 hv = *(const ushort4*)&wt_hi[gi];
                ushort4 lv = *(const ushort4*)&wt_lo[gi];
                wHs[(ocq + 0) * 72 + icl] = hv.x; wLs[(ocq + 0) * 72 + icl] = lv.x;
                wHs[(ocq + 1) * 72 + icl] = hv.y; wLs[(ocq + 1) * 72 + icl] = lv.y;
                wHs[(ocq + 2) * 72 + icl] = hv.z; wLs[(ocq + 2) * 72 + icl] = lv.z;
                wHs[(ocq + 3) * 72 + icl] = hv.w; wLs[(ocq + 3) * 72 + icl] = lv.w;
            }
            __syncthreads();

            const int off = (tap / 3) * 16 + (tap % 3);
#pragma unroll
            for (int c = 0; c < 4; ++c) {
                const int ko = c * 16 + q * 8;
                frag8 aH[2], aL[2], bH[4], bL[4];
#pragma unroll
                for (int mt = 0; mt < 2; ++mt) {
                    int oc = mh * 64 + mt * 32 + ln;
                    aH[mt] = *(const frag8*)&wHs[oc * 72 + ko];
                    aL[mt] = *(const frag8*)&wLs[oc * 72 + ko];
                }
#pragma unroll
                for (int nt = 0; nt < 4; ++nt) {
                    int pp = (posb[nt] + off) * 72 + ko;
                    bH[nt] = *(const frag8*)&inH[pp];
                    bL[nt] = *(const frag8*)&inL[pp];
                }
#pragma unroll
                for (int mt = 0; mt < 2; ++mt)
#pragma unroll
                    for (int nt = 0; nt < 4; ++nt) {
                        acc[mt][nt] = __builtin_amdgcn_mfma_f32_32x32x16_bf16(aH[mt], bH[nt], acc[mt][nt], 0, 0, 0);
                        acc[mt][nt] = __builtin_amdgcn_mfma_f32_32x32x16_bf16(aH[mt], bL[nt], acc[mt][nt], 0, 0, 0);
                        acc[mt][nt] = __builtin_amdgcn_mfma_f32_32x32x16_bf16(aL[mt], bH[nt], acc[mt][nt], 0, 0, 0);
                    }
            }
            __syncthreads();
        }
    }

#pragma unroll
    for (int mt = 0; mt < 2; ++mt)
#pragma unroll
        for (int nt = 0; nt < 4; ++nt) {
            int px = (nh * 4 + nt) * 32 + ln;
            if (px < 196) {
#pragma unroll
                for (int r = 0; r < 16; ++r) {
                    int m = (r & 3) + 8 * (r >> 2) + 4 * q;
                    int oc = mh * 64 + mt * 32 + m;
                    atomicAdd(&d1[(size_t)(b * C128 + oc) * 196 + px], acc[mt][nt][r]);
                }
            }
        }
}

// ---------------- fused tail: conv2 + conv3 + tidy1/2/3 + NMS, one block per batch ----------
// dynamic LDS layout (bytes):
//  phase A: inH@0(43776) inL@43776 wHs@87552(18432) wLs@105984 t1H@124416(2304) t1L@126720
//           d2f@129024(25088 fp32) sbuf@154112(6456 fp32)   total 160568
//  phase B (reuse 0..124416): dhH@0(27648=192*72*2) dhL@27648 d3f@55296(8192)
//           t2H@63488(2304) t2L@65792 w3H@68096(18432) w3L@86528
//  phase C: wt3s@0(4608)  phase D(NMS): y0s@6464 x0s@12928 y1s@19392 x1s@25856 ar@32320
//           rv@38784(1024) ri@39808(1024)
__global__ __launch_bounds__(256, 1) void k_tail(
    const float* __restrict__ d1,
    const unsigned short* __restrict__ w2h, const unsigned short* __restrict__ w2l,
    const unsigned short* __restrict__ w3h, const unsigned short* __restrict__ w3l,
    const float* __restrict__ b2, const float* __restrict__ b3,
    const float* __restrict__ wt1, const float* __restrict__ bt1,
    const float* __restrict__ wt2, const float* __restrict__ bt2,
    const float* __restrict__ wt3, const float* __restrict__ bt3,
    const int* __restrict__ anchors,
    float* __restrict__ score_out, float* __restrict__ out_idx,
    float* __restrict__ out_prob, int* __restrict__ idx_ws) {
    extern __shared__ char smem[];
    unsigned short* inH = (unsigned short*)(smem);
    unsigned short* inL = (unsigned short*)(smem + 43776);
    unsigned short* wHs = (unsigned short*)(smem + 87552);
    unsigned short* wLs = (unsigned short*)(smem + 105984);
    unsigned short* t1H = (unsigned short*)(smem + 124416);
    unsigned short* t1L = (unsigned short*)(smem + 126720);
    float*  d2f  = (float*)(smem + 129024);
    float*  sbuf = (float*)(smem + 154112);
    unsigned short* dhH = (unsigned short*)(smem);
    unsigned short* dhL = (unsigned short*)(smem + 27648);
    float*  d3f  = (float*)(smem + 55296);
    unsigned short* t2H = (unsigned short*)(smem + 63488);
    unsigned short* t2L = (unsigned short*)(smem + 65792);
    unsigned short* w3H = (unsigned short*)(smem + 68096);
    unsigned short* w3L = (unsigned short*)(smem + 86528);
    float* wt3s = (float*)(smem);
    float* y0s = (float*)(smem + 6464);
    float* x0s = (float*)(smem + 12928);
    float* y1s = (float*)(smem + 19392);
    float* x1s = (float*)(smem + 25856);
    float* ars = (float*)(smem + 32320);
    float* rv  = (float*)(smem + 38784);
    int*   ri  = (int*)(smem + 39808);

    const int tid = threadIdx.x;
    const int b = blockIdx.x;
    const int l = tid & 63, w = tid >> 6;
    const int ln = l & 31, q = l >> 5;
    const int l16 = l & 15, q4 = l >> 4;

    // ================= phase A: conv2 + t1 =================
    for (int i = tid; i < 304 * 72; i += 256) { inH[i] = 0; inL[i] = 0; }

    acc16 c2[2];
    acc4 t1a[4];
#pragma unroll
    for (int nt = 0; nt < 2; ++nt)
#pragma unroll
        for (int r = 0; r < 16; ++r) c2[nt][r] = 0.f;
#pragma unroll
    for (int i = 0; i < 4; ++i)
#pragma unroll
        for (int r = 0; r < 4; ++r) t1a[i][r] = 0.f;

    int posb2[2];
#pragma unroll
    for (int nt = 0; nt < 2; ++nt) {
        int p = nt * 32 + ln;
        posb2[nt] = (p < 49) ? ((p / 7) * 32 + (p % 7) * 2) : 256;
    }
    __syncthreads();

    for (int half = 0; half < 2; ++half) {
        const int ics = half * 64;
        // stage relu(d1[b]) half -> halo hi/lo
        for (int qq = tid; qq < 3136; qq += 256) {
            int icl = qq / 49, r = qq % 49, p = r * 4;
            const float4 v = *(const float4*)&d1[(size_t)(b * C128 + ics + icl) * 196 + p];
            float vv[4] = {fmaxf(v.x, 0.f), fmaxf(v.y, 0.f), fmaxf(v.z, 0.f), fmaxf(v.w, 0.f)};
#pragma unroll
            for (int e = 0; e < 4; ++e) {
                int px = p + e;
                int pos = (px / 14 + 1) * 16 + (px % 14 + 1);
                unsigned short h = f2bf(vv[e]);
                inH[pos * 72 + icl] = h;
                inL[pos * 72 + icl] = f2bf(vv[e] - bf2f(h));
            }
        }
        // stage t1 A-frag (oc 6 -> pad 16)
        for (int qq = tid; qq < 1024; qq += 256) {
            int m = qq >> 6, k = qq & 63;
            float v = (m < 6) ? wt1[m * 128 + ics + k] : 0.f;
            unsigned short h = f2bf(v);
            t1H[m * 72 + k] = h;
            t1L[m * 72 + k] = f2bf(v - bf2f(h));
        }
        __syncthreads();

        for (int tap = 0; tap < 9; ++tap) {
            for (int qq = tid; qq < 2048; qq += 256) {
                int icl = qq >> 5, ocq = (qq & 31) * 4;
                size_t gi = (size_t)(tap * C128 + ics + icl) * 128 + ocq;
                ushort4 hv = *(const ushort4*)&w2h[gi];
                ushort4 lv = *(const ushort4*)&w2l[gi];
                wHs[(ocq + 0) * 72 + icl] = hv.x; wLs[(ocq + 0) * 72 + icl] = lv.x;
                wHs[(ocq + 1) * 72 + icl] = hv.y; wLs[(ocq + 1) * 72 + icl] = lv.y;
                wHs[(ocq + 2) * 72 + icl] = hv.z; wLs[(ocq + 2) * 72 + icl] = lv.z;
                wHs[(ocq + 3) * 72 + icl] = hv.w; wLs[(ocq + 3) * 72 + icl] = lv.w;
            }
            __syncthreads();
            const int off = (tap / 3) * 16 + (tap % 3);
#pragma unroll
            for (int c = 0; c < 4; ++c) {
                const int ko = c * 16 + q * 8;
                frag8 aH = *(const frag8*)&wHs[(w * 32 + ln) * 72 + ko];
                frag8 aL = *(const frag8*)&wLs[(w * 32 + ln) * 72 + ko];
#pragma unroll
                for (int nt = 0; nt < 2; ++nt) {
                    int pp = (posb2[nt] + off) * 72 + ko;
                    frag8 bH = *(const frag8*)&inH[pp];
                    frag8 bL = *(const frag8*)&inL[pp];
                    c2[nt] = __builtin_amdgcn_mfma_f32_32x32x16_bf16(aH, bH, c2[nt], 0, 0, 0);
                    c2[nt] = __builtin_amdgcn_mfma_f32_32x32x16_bf16(aH, bL, c2[nt], 0, 0, 0);
                    c2[nt] = __builtin_amdgcn_mfma_f32_32x32x16_bf16(aL, bH, c2[nt], 0, 0, 0);
                }
            }
            __syncthreads();
        }

        // t1 MFMA on this half (inH intact since last barrier)
#pragma unroll
        for (int i = 0; i < 4; ++i) {
            int px = (w * 4 + i) * 16 + l16;
            int pos = (px < 196) ? ((px / 14 + 1) * 16 + (px % 14 + 1)) : 256;
#pragma unroll
            for (int c = 0; c < 2; ++c) {
                int ko = c * 32 + q4 * 8;
                frag8 aH = *(const frag8*)&t1H[l16 * 72 + ko];
                frag8 aL = *(const frag8*)&t1L[l16 * 72 + ko];
                frag8 bH = *(const frag8*)&inH[pos * 72 + ko];
                frag8 bL = *(const frag8*)&inL[pos * 72 + ko];
                t1a[i] = __builtin_amdgcn_mfma_f32_16x16x32_bf16(aH, bH, t1a[i], 0, 0, 0);
                t1a[i] = __builtin_amdgcn_mfma_f32_16x16x32_bf16(aH, bL, t1a[i], 0, 0, 0);
                t1a[i] = __builtin_amdgcn_mfma_f32_16x16x32_bf16(aL, bH, t1a[i], 0, 0, 0);
            }
        }
        __syncthreads();
    }

    // conv2 epilogue -> d2f (bias + relu), stays in LDS
#pragma unroll
    for (int nt = 0; nt < 2; ++nt) {
        int p = nt * 32 + ln;
        if (p < 49) {
#pragma unroll
            for (int r = 0; r < 16; ++r) {
                int m = (r & 3) + 8 * (r >> 2) + 4 * q;
                int oc = w * 32 + m;
                d2f[oc * 49 + p] = fmaxf(c2[nt][r] + b2[oc], 0.f);
            }
        }
    }
    // t1 epilogue -> scores
#pragma unroll
    for (int i = 0; i < 4; ++i) {
        int px = (w * 4 + i) * 16 + l16;
#pragma unroll
        for (int r = 0; r < 4; ++r) {
            int oc = q4 * 4 + r;
            if (oc < 6 && px < 196) {
                float v = t1a[i][r] + bt1[oc];
                sbuf[oc * 196 + px] = v;
                score_out[b * NA + oc * 196 + px] = v;
            }
        }
    }
    __syncthreads();

    // ================= phase B: conv3 + t2 =================
    for (int i = tid; i < 192 * 72; i += 256) { dhH[i] = 0; dhL[i] = 0; }

    acc16 c3;
    acc4 t2a;
#pragma unroll
    for (int r = 0; r < 16; ++r) c3[r] = 0.f;
#pragma unroll
    for (int r = 0; r < 4; ++r) t2a[r] = 0.f;

    const int posb3 = (ln < 16) ? ((ln / 4) * 32 + (ln % 4) * 2) : 144;
    const int pxt2 = w * 16 + l16;
    const int posbt2 = (pxt2 < 49) ? ((pxt2 / 7 + 1) * 16 + (pxt2 % 7 + 1)) : 144;
    __syncthreads();

    for (int half = 0; half < 2; ++half) {
        const int ics = half * 64;
        for (int qq = tid; qq < 3136; qq += 256) {
            int icl = qq / 49, p = qq % 49;
            float v = d2f[(ics + icl) * 49 + p];
            int pos = (p / 7 + 1) * 16 + (p % 7 + 1);
            unsigned short h = f2bf(v);
            dhH[pos * 72 + icl] = h;
            dhL[pos * 72 + icl] = f2bf(v - bf2f(h));
        }
        for (int qq = tid; qq < 1024; qq += 256) {
            int m = qq >> 6, k = qq & 63;
            float v = (m < 6) ? wt2[m * 128 + ics + k] : 0.f;
            unsigned short h = f2bf(v);
            t2H[m * 72 + k] = h;
            t2L[m * 72 + k] = f2bf(v - bf2f(h));
        }
        __syncthreads();

        for (int tap = 0; tap < 9; ++tap) {
            for (int qq = tid; qq < 2048; qq += 256) {
                int icl = qq >> 5, ocq = (qq & 31) * 4;
                size_t gi = (size_t)(tap * C128 + ics + icl) * 128 + ocq;
                ushort4 hv = *(const ushort4*)&w3h[gi];
                ushort4 lv = *(const ushort4*)&w3l[gi];
                w3H[(ocq + 0) * 72 + icl] = hv.x; w3L[(ocq + 0) * 72 + icl] = lv.x;
                w3H[(ocq + 1) * 72 + icl] = hv.y; w3L[(ocq + 1) * 72 + icl] = lv.y;
                w3H[(ocq + 2) * 72 + icl] = hv.z; w3L[(ocq + 2) * 72 + icl] = lv.z;
                w3H[(ocq + 3) * 72 + icl] = hv.w; w3L[(ocq + 3) * 72 + icl] = lv.w;
            }
            __syncthreads();
            const int off = (tap / 3) * 16 + (tap % 3);
#pragma unroll
            for (int c = 0; c < 4; ++c) {
                const int ko = c * 16 + q * 8;
                frag8 aH = *(const frag8*)&w3H[(w * 32 + ln) * 72 + ko];
                frag8 aL = *(const frag8*)&w3L[(w * 32 + ln) * 72 + ko];
                int pp = (posb3 + off) * 72 + ko;
                frag8 bH = *(const frag8*)&dhH[pp];
                frag8 bL = *(const frag8*)&dhL[pp];
                c3 = __builtin_amdgcn_mfma_f32_32x32x16_bf16(aH, bH, c3, 0, 0, 0);
                c3 = __builtin_amdgcn_mfma_f32_32x32x16_bf16(aH, bL, c3, 0, 0, 0);
                c3 = __builtin_amdgcn_mfma_f32_32x32x16_bf16(aL, bH, c3, 0, 0, 0);
            }
            __syncthreads();
        }

        // t2 MFMA on this half
#pragma unroll
        for (int c = 0; c < 2; ++c) {
            int ko = c * 32 + q4 * 8;
            frag8 aH = *(const frag8*)&t2H[l16 * 72 + ko];
            frag8 aL = *(const frag8*)&t2L[l16 * 72 + ko];
            frag8 bH = *(const frag8*)&dhH[posbt2 * 72 + ko];
            frag8 bL = *(const frag8*)&dhL[posbt2 * 72 + ko];
            t2a = __builtin_amdgcn_mfma_f32_16x16x32_bf16(aH, bH, t2a, 0, 0, 0);
            t2a = __builtin_amdgcn_mfma_f32_16x16x32_bf16(aH, bL, t2a, 0, 0, 0);
            t2a = __builtin_amdgcn_mfma_f32_16x16x32_bf16(aL, bH, t2a, 0, 0, 0);
        }
        __syncthreads();
    }

    // conv3 epilogue -> d3f
    {
        int p = ln;
        if (p < 16) {
#pragma unroll
            for (int r = 0; r < 16; ++r) {
                int m = (r & 3) + 8 * (r >> 2) + 4 * q;
                int oc = w * 32 + m;
                d3f[oc * 16 + p] = fmaxf(c3[r] + b3[oc], 0.f);
            }
        }
    }
    // t2 epilogue -> scores
#pragma unroll
    for (int r = 0; r < 4; ++r) {
        int oc = q4 * 4 + r;
        if (oc < 6 && pxt2 < 49) {
            float v = t2a[r] + bt2[oc];
            sbuf[1176 + oc * 49 + pxt2] = v;
            score_out[b * NA + 1176 + oc * 49 + pxt2] = v;
        }
    }
    // stage wt3 (overwrites dead dhH region)
    for (int i = tid; i < 1152; i += 256) wt3s[i] = wt3[i];
    __syncthreads();

    // ================= phase C: t3 (VALU) + anchor staging =================
    if (tid < 144) {
        int oc = tid >> 4, px = tid & 15;
        float s = bt3[oc];
        for (int ic = 0; ic < 128; ++ic) s += wt3s[oc * 128 + ic] * d3f[ic * 16 + px];
        sbuf[1470 + oc * 16 + px] = s;
        score_out[b * NA + 1470 + oc * 16 + px] = s;
    }
    for (int j = tid; j < NA; j += 256) {
        int4 a = ((const int4*)anchors)[j];
        float a0 = (float)a.x, a1 = (float)a.y, a2 = (float)a.z, a3 = (float)a.w;
        y0s[j] = a0; x0s[j] = a1; y1s[j] = a2; x1s[j] = a3;
        ars[j] = (a2 - a0) * (a3 - a1);
    }
    __syncthreads();

    // ================= phase D: greedy hard-NMS top-4 =================
    for (int it = 0; it < TOPN; ++it) {
        float bv = -INFINITY; int bi = NA;
        for (int j = tid; j < NA; j += 256) {
            float v = sbuf[j];
            if (v > bv || (v == bv && j < bi)) { bv = v; bi = j; }
        }
        rv[tid] = bv; ri[tid] = bi;
        __syncthreads();
        for (int off = 128; off > 0; off >>= 1) {
            if (tid < off) {
                float ov = rv[tid + off]; int oi = ri[tid + off];
                if (ov > rv[tid] || (ov == rv[tid] && oi < ri[tid])) { rv[tid] = ov; ri[tid] = oi; }
            }
            __syncthreads();
        }
        int K = ri[0]; float V = rv[0];
        if (tid == 0) {
            out_idx[b * TOPN + it] = (float)K;
            out_prob[b * TOPN + it] = V;
            idx_ws[b * TOPN + it] = K;
        }
        float ky0 = y0s[K], kx0 = x0s[K], ky1 = y1s[K], kx1 = x1s[K], ka = ars[K];
        for (int j = tid; j < NA; j += 256) {
            float iy = fmaxf(fminf(y1s[j], ky1) - fmaxf(y0s[j], ky0), 0.f);
            float ix = fmaxf(fminf(x1s[j], kx1) - fmaxf(x0s[j], kx0), 0.f);
            float inter = iy * ix;
            float iou = inter / (ars[j] + ka - inter);
            if (iou >= 0.25f) sbuf[j] = -INFINITY;
        }
        __syncthreads();
    }
}

// ---------------- bilinear crop-resize ----------------
__global__ __launch_bounds__(256) void k_crop(const float* __restrict__ x,
                                              const int* __restrict__ anchors,
                                              const int* __restrict__ idx_ws,
                                              float* __restrict__ out) {
    int blk = blockIdx.x;
    int crop = blk / OUTS;
    int i = blk % OUTS;
    int j = threadIdx.x;
    if (j >= OUTS) return;
    int b = crop >> 2;
    int a = idx_ws[crop];
    int y0 = anchors[a * 4], x0 = anchors[a * 4 + 1];
    int y1 = anchors[a * 4 + 2], x1 = anchors[a * 4 + 3];

    float ti = (float)i / 223.f;
    float ys = (float)y0 + ti * (float)(y1 - y0 - 1);
    int yi0 = (int)ys;
    int yi1 = min(yi0 + 1, HP - 1);
    float wy = ys - (float)yi0;

    float tj = (float)j / 223.f;
    float xs = (float)x0 + tj * (float)(x1 - x0 - 1);
    int xi0 = (int)xs;
    int xi1 = min(xi0 + 1, HP - 1);
    float wx = xs - (float)xi0;

    int ry0 = yi0 - PADW, ry1 = yi1 - PADW, rx0 = xi0 - PADW, rx1 = xi1 - PADW;
    bool vy0 = (ry0 >= 0) && (ry0 < IM), vy1 = (ry1 >= 0) && (ry1 < IM);
    bool vx0 = (rx0 >= 0) && (rx0 < IM), vx1 = (rx1 >= 0) && (rx1 < IM);

    float w00 = (1.f - wy) * (1.f - wx), w01 = (1.f - wy) * wx;
    float w10 = wy * (1.f - wx), w11 = wy * wx;

#pragma unroll
    for (int c = 0; c < 3; ++c) {
        const float* xp = x + (size_t)(b * 3 + c) * IM * IM;
        float g00 = (vy0 && vx0) ? xp[ry0 * IM + rx0] : 0.f;
        float g01 = (vy0 && vx1) ? xp[ry0 * IM + rx1] : 0.f;
        float g10 = (vy1 && vx0) ? xp[ry1 * IM + rx0] : 0.f;
        float g11 = (vy1 && vx1) ? xp[ry1 * IM + rx1] : 0.f;
        out[(size_t)(crop * 3 + c) * OUTS * OUTS + i * OUTS + j] =
            g00 * w00 + g01 * w01 + g10 * w10 + g11 * w11;
    }
}

extern "C" void kernel_launch(void* const* d_in, const int* in_sizes, int n_in,
                              void* d_out, int out_size, void* d_ws, size_t ws_size,
                              hipStream_t stream) {
    (void)in_sizes; (void)n_in; (void)out_size; (void)ws_size;
    const float* x    = (const float*)d_in[0];
    const float* rpn  = (const float*)d_in[1];
    const float* w1   = (const float*)d_in[2];
    const float* b1   = (const float*)d_in[3];
    const float* w2   = (const float*)d_in[4];
    const float* b2   = (const float*)d_in[5];
    const float* w3   = (const float*)d_in[6];
    const float* b3   = (const float*)d_in[7];
    const float* wt1  = (const float*)d_in[8];
    const float* bt1  = (const float*)d_in[9];
    const float* wt2  = (const float*)d_in[10];
    const float* bt2  = (const float*)d_in[11];
    const float* wt3  = (const float*)d_in[12];
    const float* bt3  = (const float*)d_in[13];
    const int*   anc  = (const int*)d_in[14];

    float* out = (float*)d_out;
    float* ws  = (float*)d_ws;
    float* d1  = ws + WS_D1;
    int*   idxw = (int*)(ws + WS_IDX);
    unsigned short* w1h = (unsigned short*)(ws + WS_WT);
    unsigned short* w1l = w1h + NWT1;
    unsigned short* w2h = w1l + NWT1;
    unsigned short* w2l = w2h + NWT2;
    unsigned short* w3h = w2l + NWT2;
    unsigned short* w3l = w3h + NWT2;

    static const int TAIL_LDS = 160568;
    hipFuncSetAttribute((const void*)k_tail, hipFuncAttributeMaxDynamicSharedMemorySize, TAIL_LDS);

    k_wrepack<<<1024, 256, 0, stream>>>(w1, w1h, w1l, IC1);
    k_wrepack<<<64, 256, 0, stream>>>(w2, w2h, w2l, C128);
    k_wrepack<<<64, 256, 0, stream>>>(w3, w3h, w3l, C128);
    k_init_d1<<<(BATCH * C128 * 196 + 255) / 256, 256, 0, stream>>>(d1, b1);
    k_conv1_mfma<<<256, 256, 0, stream>>>(rpn, w1h, w1l, d1);
    k_tail<<<BATCH, 256, TAIL_LDS, stream>>>(d1, w2h, w2l, w3h, w3l, b2, b3,
                                             wt1, bt1, wt2, bt2, wt3, bt3, anc,
                                             out + OFF_SCORE, out + OFF_TOPIDX,
                                             out + OFF_TOPPROB, idxw);
    k_crop<<<BATCH * TOPN * OUTS, 256, 0, stream>>>(x, anc, idxw, out);
}

// Round 4
// 369.894 us; speedup vs baseline: 2.2369x; 1.3262x over previous
//
#include <hip/hip_runtime.h>
#include <math.h>

#define BATCH 16
#define TOPN 4
#define OUTS 224
#define PADW 224
#define IM 448
#define HP 896
#define NA 1614
#define IC1 2048
#define C128 128

// d_out float offsets
#define N_PART (BATCH*TOPN*3*OUTS*OUTS)       // 9,633,792
#define OFF_TOPIDX  (N_PART)
#define OFF_TOPPROB (N_PART + BATCH*TOPN)
#define OFF_SCORE   (N_PART + 2*BATCH*TOPN)

// ws float offsets.  d1 is [b][px 196][oc 128]
#define WS_D1 0
#define WS_IDX (BATCH*C128*196)                // 64 ints
#define WS_WT  (WS_IDX + 64)                   // repacked weights (ushort)
#define NWT1 (9*2048*128)
#define NWT2 (9*128*128)

typedef __attribute__((ext_vector_type(8))) short frag8;     // 8 bf16 (4 VGPRs)
typedef __attribute__((ext_vector_type(16))) float acc16;    // 16 fp32 acc (32x32)
typedef __attribute__((ext_vector_type(4)))  float acc4;     // 4 fp32 acc (16x16)

__device__ __forceinline__ unsigned short f2bf(float f) {
    unsigned int u = __float_as_uint(f);
    u = (u + 0x7fffu + ((u >> 16) & 1u)) >> 16;   // RNE
    return (unsigned short)u;
}
__device__ __forceinline__ float bf2f(unsigned short h) {
    return __uint_as_float(((unsigned int)h) << 16);
}
__device__ __forceinline__ void cvt4(const float* v, ushort4* h, ushort4* lo) {
    unsigned short hh[4], ll[4];
#pragma unroll
    for (int e = 0; e < 4; ++e) { hh[e] = f2bf(v[e]); ll[e] = f2bf(v[e] - bf2f(hh[e])); }
    *h  = make_ushort4(hh[0], hh[1], hh[2], hh[3]);
    *lo = make_ushort4(ll[0], ll[1], ll[2], ll[3]);
}

// ---------------- init d1 with bias (d1 layout [b][px][oc]) ----------------
__global__ void k_init_d1(float* __restrict__ d1, const float* __restrict__ b1) {
    int i = blockIdx.x * 256 + threadIdx.x;
    if (i < BATCH * C128 * 196) d1[i] = b1[i & 127];
}

// ---------------- weight repack: w[oc][ic][tap] fp32 -> [tap][oc][ic] bf16 hi/lo ----------
__global__ __launch_bounds__(256) void k_wrepack(const float* __restrict__ w,
                                                 unsigned short* __restrict__ w_hi,
                                                 unsigned short* __restrict__ w_lo,
                                                 int IC) {
    int i = blockIdx.x * 256 + threadIdx.x;
    if (i >= 128 * IC) return;
    int oc = i / IC, ic = i % IC;
    const float* src = w + (size_t)(oc * IC + ic) * 9;
#pragma unroll
    for (int tap = 0; tap < 9; ++tap) {
        float v = src[tap];
        unsigned short h = f2bf(v);
        size_t gi = ((size_t)tap * 128 + oc) * IC + ic;
        w_hi[gi] = h;
        w_lo[gi] = f2bf(v - bf2f(h));
    }
}

// ---------------- conv1 via MFMA 32x32x16 bf16 (A=input px, B=weight oc) ----------------
// grid 256: blockIdx.x = kg*16 + b; block 256 thr = 4 waves
// wave w owns M-tiles {2w, 2w+1} (px, padded 196->256) x all 4 N-tiles (oc)
__global__ __launch_bounds__(256, 1) void k_conv1_mfma(const float* __restrict__ rpn,
                                                       const unsigned short* __restrict__ wt_hi,
                                                       const unsigned short* __restrict__ wt_lo,
                                                       float* __restrict__ d1) {
    __shared__ unsigned short inH[304 * 72];   // [pos][ic64]
    __shared__ unsigned short inL[304 * 72];
    __shared__ unsigned short wHs[128 * 72];   // [oc][ic64]
    __shared__ unsigned short wLs[128 * 72];

    const int tid = threadIdx.x;
    const int b = blockIdx.x & 15, kg = blockIdx.x >> 4;
    const int l = tid & 63, w = tid >> 6;
    const int ln = l & 31, q = l >> 5;

    for (int i = tid; i < 304 * 72; i += 256) { inH[i] = 0; inL[i] = 0; }

    acc16 acc[2][4];
#pragma unroll
    for (int mt = 0; mt < 2; ++mt)
#pragma unroll
        for (int nt = 0; nt < 4; ++nt)
#pragma unroll
            for (int r = 0; r < 16; ++r) acc[mt][nt][r] = 0.f;

    int posa[2];
#pragma unroll
    for (int mt = 0; mt < 2; ++mt) {
        int px = (w * 2 + mt) * 32 + ln;
        posa[mt] = (px < 196) ? ((px / 14) * 16 + (px % 14)) : 256;  // 256 -> zero region
    }
    __syncthreads();

    for (int half = 0; half < 2; ++half) {
        const int ics = kg * 128 + half * 64;
        // stage input: rpn[b][ic][px] -> inH/inL [pos][icl]  (transpose scatter, scalar)
        for (int qq = tid; qq < 3136; qq += 256) {
            int icl = qq / 49, r = qq % 49, p = r * 4;
            const float4 v = *(const float4*)&rpn[(size_t)(b * IC1 + ics + icl) * 196 + p];
            float vv[4] = {v.x, v.y, v.z, v.w};
#pragma unroll
            for (int e = 0; e < 4; ++e) {
                int px = p + e;
                int pos = (px / 14 + 1) * 16 + (px % 14 + 1);
                unsigned short h = f2bf(vv[e]);
                inH[pos * 72 + icl] = h;
                inL[pos * 72 + icl] = f2bf(vv[e] - bf2f(h));
            }
        }
        __syncthreads();

        for (int tap = 0; tap < 9; ++tap) {
            // stage weights [tap][oc][ic] -> wHs/wLs [oc][icl]  (vector, conflict-free)
            for (int qq = tid; qq < 2048; qq += 256) {
                int oc = qq >> 4, ic4 = (qq & 15) * 4;
                size_t gi = ((size_t)tap * 128 + oc) * IC1 + ics + ic4;
                *(ushort4*)&wHs[oc * 72 + ic4] = *(const ushort4*)&wt_hi[gi];
                *(ushort4*)&wLs[oc * 72 + ic4] = *(const ushort4*)&wt_lo[gi];
            }
            __syncthreads();

            const int off = (tap / 3) * 16 + (tap % 3);
#pragma unroll
            for (int c = 0; c < 4; ++c) {
                const int ko = c * 16 + q * 8;
                frag8 aH[2], aL[2], bH[4], bL[4];
#pragma unroll
                for (int mt = 0; mt < 2; ++mt) {
                    int pp = (posa[mt] + off) * 72 + ko;
                    aH[mt] = *(const frag8*)&inH[pp];
                    aL[mt] = *(const frag8*)&inL[pp];
                }
#pragma unroll
                for (int nt = 0; nt < 4; ++nt) {
                    int oc = nt * 32 + ln;
                    bH[nt] = *(const frag8*)&wHs[oc * 72 + ko];
                    bL[nt] = *(const frag8*)&wLs[oc * 72 + ko];
                }
#pragma unroll
                for (int mt = 0; mt < 2; ++mt)
#pragma unroll
                    for (int nt = 0; nt < 4; ++nt) {
                        acc[mt][nt] = __builtin_amdgcn_mfma_f32_32x32x16_bf16(aH[mt], bH[nt], acc[mt][nt], 0, 0, 0);
                        acc[mt][nt] = __builtin_amdgcn_mfma_f32_32x32x16_bf16(aH[mt], bL[nt], acc[mt][nt], 0, 0, 0);
                        acc[mt][nt] = __builtin_amdgcn_mfma_f32_32x32x16_bf16(aL[mt], bH[nt], acc[mt][nt], 0, 0, 0);
                    }
            }
            __syncthreads();
        }
    }

    // epilogue: C row = px, col = oc -> coalesced atomics on d1[b][px][oc]
#pragma unroll
    for (int mt = 0; mt < 2; ++mt)
#pragma unroll
        for (int nt = 0; nt < 4; ++nt) {
#pragma unroll
            for (int r = 0; r < 16; ++r) {
                int m = (r & 3) + 8 * (r >> 2) + 4 * q;
                int px = (w * 2 + mt) * 32 + m;
                if (px < 196)
                    atomicAdd(&d1[(size_t)(b * 196 + px) * 128 + nt * 32 + ln], acc[mt][nt][r]);
            }
        }
}

// ---------------- fused tail: conv2 + conv3 + tidy1/2/3 + NMS, one block per batch ----------
__global__ __launch_bounds__(256, 1) void k_tail(
    const float* __restrict__ d1,
    const unsigned short* __restrict__ w2h, const unsigned short* __restrict__ w2l,
    const unsigned short* __restrict__ w3h, const unsigned short* __restrict__ w3l,
    const float* __restrict__ b2, const float* __restrict__ b3,
    const float* __restrict__ wt1, const float* __restrict__ bt1,
    const float* __restrict__ wt2, const float* __restrict__ bt2,
    const float* __restrict__ wt3, const float* __restrict__ bt3,
    const int* __restrict__ anchors,
    float* __restrict__ score_out, float* __restrict__ out_idx,
    float* __restrict__ out_prob, int* __restrict__ idx_ws) {
    extern __shared__ char smem[];
    unsigned short* inH = (unsigned short*)(smem);            // [pos 304][ic 72]
    unsigned short* inL = (unsigned short*)(smem + 43776);
    unsigned short* wHs = (unsigned short*)(smem + 87552);    // [oc 128][ic 72]
    unsigned short* wLs = (unsigned short*)(smem + 105984);
    unsigned short* t1H = (unsigned short*)(smem + 124416);   // [oc16][ic 72]
    unsigned short* t1L = (unsigned short*)(smem + 126720);
    float*  d2f  = (float*)(smem + 129024);                   // [px 49][oc 128]
    float*  sbuf = (float*)(smem + 154112);                   // [1614]
    unsigned short* dhH = (unsigned short*)(smem);            // [pos 192][ic 72]
    unsigned short* dhL = (unsigned short*)(smem + 27648);
    float*  d3f  = (float*)(smem + 55296);                    // [ic 128][px 16]
    unsigned short* t2H = (unsigned short*)(smem + 63488);
    unsigned short* t2L = (unsigned short*)(smem + 65792);
    unsigned short* w3H = (unsigned short*)(smem + 68096);
    unsigned short* w3L = (unsigned short*)(smem + 86528);
    float* wt3s = (float*)(smem);
    float* y0s = (float*)(smem + 6464);
    float* x0s = (float*)(smem + 12928);
    float* y1s = (float*)(smem + 19392);
    float* x1s = (float*)(smem + 25856);
    float* ars = (float*)(smem + 32320);
    float* rv  = (float*)(smem + 38784);
    int*   ri  = (int*)(smem + 39808);

    const int tid = threadIdx.x;
    const int b = blockIdx.x;
    const int l = tid & 63, w = tid >> 6;
    const int ln = l & 31, q = l >> 5;
    const int l16 = l & 15, q4 = l >> 4;

    // ================= phase A: conv2 + t1 =================
    for (int i = tid; i < 304 * 72; i += 256) { inH[i] = 0; inL[i] = 0; }

    acc16 c2[2];
    acc4 t1a[4];
#pragma unroll
    for (int nt = 0; nt < 2; ++nt)
#pragma unroll
        for (int r = 0; r < 16; ++r) c2[nt][r] = 0.f;
#pragma unroll
    for (int i = 0; i < 4; ++i)
#pragma unroll
        for (int r = 0; r < 4; ++r) t1a[i][r] = 0.f;

    // A-operand (input) pos: wave w -> M-tile mt = w&1; N-tiles {2*(w>>1), 2*(w>>1)+1}
    const int mtw = w & 1, ntw = w >> 1;
    int posa2;
    {
        int px = mtw * 32 + ln;
        posa2 = (px < 49) ? ((px / 7) * 32 + (px % 7) * 2) : 256;
    }
    __syncthreads();

    for (int half = 0; half < 2; ++half) {
        const int ics = half * 64;
        // stage relu(d1[b][px][ic]) -> inH/inL [pos][icl]   (vector, conflict-free)
        for (int qq = tid; qq < 3136; qq += 256) {
            int px = qq >> 4, ic4 = (qq & 15) * 4;
            float4 v = *(const float4*)&d1[(size_t)(b * 196 + px) * 128 + ics + ic4];
            float vv[4] = {fmaxf(v.x, 0.f), fmaxf(v.y, 0.f), fmaxf(v.z, 0.f), fmaxf(v.w, 0.f)};
            ushort4 h4, l4; cvt4(vv, &h4, &l4);
            int pos = (px / 14 + 1) * 16 + (px % 14 + 1);
            *(ushort4*)&inH[pos * 72 + ic4] = h4;
            *(ushort4*)&inL[pos * 72 + ic4] = l4;
        }
        // stage t1 A-frag (oc 6 -> pad 16)
        for (int qq = tid; qq < 1024; qq += 256) {
            int m = qq >> 6, k = qq & 63;
            float v = (m < 6) ? wt1[m * 128 + ics + k] : 0.f;
            unsigned short h = f2bf(v);
            t1H[m * 72 + k] = h;
            t1L[m * 72 + k] = f2bf(v - bf2f(h));
        }
        __syncthreads();

        for (int tap = 0; tap < 9; ++tap) {
            for (int qq = tid; qq < 2048; qq += 256) {
                int oc = qq >> 4, ic4 = (qq & 15) * 4;
                size_t gi = ((size_t)tap * 128 + oc) * C128 + ics + ic4;
                *(ushort4*)&wHs[oc * 72 + ic4] = *(const ushort4*)&w2h[gi];
                *(ushort4*)&wLs[oc * 72 + ic4] = *(const ushort4*)&w2l[gi];
            }
            __syncthreads();
            const int off = (tap / 3) * 16 + (tap % 3);
#pragma unroll
            for (int c = 0; c < 4; ++c) {
                const int ko = c * 16 + q * 8;
                int pp = (posa2 + off) * 72 + ko;
                frag8 aH = *(const frag8*)&inH[pp];
                frag8 aL = *(const frag8*)&inL[pp];
#pragma unroll
                for (int nt = 0; nt < 2; ++nt) {
                    int oc = (ntw * 2 + nt) * 32 + ln;
                    frag8 bH = *(const frag8*)&wHs[oc * 72 + ko];
                    frag8 bL = *(const frag8*)&wLs[oc * 72 + ko];
                    c2[nt] = __builtin_amdgcn_mfma_f32_32x32x16_bf16(aH, bH, c2[nt], 0, 0, 0);
                    c2[nt] = __builtin_amdgcn_mfma_f32_32x32x16_bf16(aH, bL, c2[nt], 0, 0, 0);
                    c2[nt] = __builtin_amdgcn_mfma_f32_32x32x16_bf16(aL, bH, c2[nt], 0, 0, 0);
                }
            }
            __syncthreads();
        }

        // t1 MFMA on this half (inH intact since last barrier): A=wt1, B=input -> col=px,row=oc
#pragma unroll
        for (int i = 0; i < 4; ++i) {
            int px = (w * 4 + i) * 16 + l16;
            int pos = (px < 196) ? ((px / 14 + 1) * 16 + (px % 14 + 1)) : 256;
#pragma unroll
            for (int c = 0; c < 2; ++c) {
                int ko = c * 32 + q4 * 8;
                frag8 aH = *(const frag8*)&t1H[l16 * 72 + ko];
                frag8 aL = *(const frag8*)&t1L[l16 * 72 + ko];
                frag8 bH = *(const frag8*)&inH[pos * 72 + ko];
                frag8 bL = *(const frag8*)&inL[pos * 72 + ko];
                t1a[i] = __builtin_amdgcn_mfma_f32_16x16x32_bf16(aH, bH, t1a[i], 0, 0, 0);
                t1a[i] = __builtin_amdgcn_mfma_f32_16x16x32_bf16(aH, bL, t1a[i], 0, 0, 0);
                t1a[i] = __builtin_amdgcn_mfma_f32_16x16x32_bf16(aL, bH, t1a[i], 0, 0, 0);
            }
        }
        __syncthreads();
    }

    // conv2 epilogue -> d2f[px][oc] (bias + relu), stays in LDS
#pragma unroll
    for (int nt = 0; nt < 2; ++nt) {
        int oc = (ntw * 2 + nt) * 32 + ln;
        float bias = b2[oc];
#pragma unroll
        for (int r = 0; r < 16; ++r) {
            int m = (r & 3) + 8 * (r >> 2) + 4 * q;
            int px = mtw * 32 + m;
            if (px < 49) d2f[px * 128 + oc] = fmaxf(c2[nt][r] + bias, 0.f);
        }
    }
    // t1 epilogue -> scores
#pragma unroll
    for (int i = 0; i < 4; ++i) {
        int px = (w * 4 + i) * 16 + l16;
#pragma unroll
        for (int r = 0; r < 4; ++r) {
            int oc = q4 * 4 + r;
            if (oc < 6 && px < 196) {
                float v = t1a[i][r] + bt1[oc];
                sbuf[oc * 196 + px] = v;
                score_out[b * NA + oc * 196 + px] = v;
            }
        }
    }
    __syncthreads();

    // ================= phase B: conv3 + t2 =================
    for (int i = tid; i < 192 * 72; i += 256) { dhH[i] = 0; dhL[i] = 0; }

    acc16 c3;
    acc4 t2a;
#pragma unroll
    for (int r = 0; r < 16; ++r) c3[r] = 0.f;
#pragma unroll
    for (int r = 0; r < 4; ++r) t2a[r] = 0.f;

    const int posb3 = (ln < 16) ? ((ln / 4) * 32 + (ln % 4) * 2) : 144;
    const int pxt2 = w * 16 + l16;
    const int posbt2 = (pxt2 < 49) ? ((pxt2 / 7 + 1) * 16 + (pxt2 % 7 + 1)) : 144;
    __syncthreads();

    for (int half = 0; half < 2; ++half) {
        const int ics = half * 64;
        // stage d2f[px][ic] -> dhH/dhL [pos][icl]  (LDS->LDS, vector, conflict-free)
        for (int qq = tid; qq < 784; qq += 256) {
            int px = qq >> 4, ic4 = (qq & 15) * 4;
            float4 v = *(const float4*)&d2f[px * 128 + ics + ic4];
            float vv[4] = {v.x, v.y, v.z, v.w};
            ushort4 h4, l4; cvt4(vv, &h4, &l4);
            int pos = (px / 7 + 1) * 16 + (px % 7 + 1);
            *(ushort4*)&dhH[pos * 72 + ic4] = h4;
            *(ushort4*)&dhL[pos * 72 + ic4] = l4;
        }
        for (int qq = tid; qq < 1024; qq += 256) {
            int m = qq >> 6, k = qq & 63;
            float v = (m < 6) ? wt2[m * 128 + ics + k] : 0.f;
            unsigned short h = f2bf(v);
            t2H[m * 72 + k] = h;
            t2L[m * 72 + k] = f2bf(v - bf2f(h));
        }
        __syncthreads();

        for (int tap = 0; tap < 9; ++tap) {
            for (int qq = tid; qq < 2048; qq += 256) {
                int oc = qq >> 4, ic4 = (qq & 15) * 4;
                size_t gi = ((size_t)tap * 128 + oc) * C128 + ics + ic4;
                *(ushort4*)&w3H[oc * 72 + ic4] = *(const ushort4*)&w3h[gi];
                *(ushort4*)&w3L[oc * 72 + ic4] = *(const ushort4*)&w3l[gi];
            }
            __syncthreads();
            const int off = (tap / 3) * 16 + (tap % 3);
#pragma unroll
            for (int c = 0; c < 4; ++c) {
                const int ko = c * 16 + q * 8;
                int pp = (posb3 + off) * 72 + ko;
                frag8 aH = *(const frag8*)&dhH[pp];
                frag8 aL = *(const frag8*)&dhL[pp];
                int oc = w * 32 + ln;
                frag8 bH = *(const frag8*)&w3H[oc * 72 + ko];
                frag8 bL = *(const frag8*)&w3L[oc * 72 + ko];
                c3 = __builtin_amdgcn_mfma_f32_32x32x16_bf16(aH, bH, c3, 0, 0, 0);
                c3 = __builtin_amdgcn_mfma_f32_32x32x16_bf16(aH, bL, c3, 0, 0, 0);
                c3 = __builtin_amdgcn_mfma_f32_32x32x16_bf16(aL, bH, c3, 0, 0, 0);
            }
            __syncthreads();
        }

        // t2 MFMA on this half
#pragma unroll
        for (int c = 0; c < 2; ++c) {
            int ko = c * 32 + q4 * 8;
            frag8 aH = *(const frag8*)&t2H[l16 * 72 + ko];
            frag8 aL = *(const frag8*)&t2L[l16 * 72 + ko];
            frag8 bH = *(const frag8*)&dhH[posbt2 * 72 + ko];
            frag8 bL = *(const frag8*)&dhL[posbt2 * 72 + ko];
            t2a = __builtin_amdgcn_mfma_f32_16x16x32_bf16(aH, bH, t2a, 0, 0, 0);
            t2a = __builtin_amdgcn_mfma_f32_16x16x32_bf16(aH, bL, t2a, 0, 0, 0);
            t2a = __builtin_amdgcn_mfma_f32_16x16x32_bf16(aL, bH, t2a, 0, 0, 0);
        }
        __syncthreads();
    }

    // conv3 epilogue -> d3f[ic][px]  (row=px, col=oc; stride-16 writes = 2-way, free)
    {
        int oc = w * 32 + ln;
        float bias = b3[oc];
#pragma unroll
        for (int r = 0; r < 16; ++r) {
            int px = (r & 3) + 8 * (r >> 2) + 4 * q;
            if (px < 16) d3f[oc * 16 + px] = fmaxf(c3[r] + bias, 0.f);
        }
    }
    // t2 epilogue -> scores
#pragma unroll
    for (int r = 0; r < 4; ++r) {
        int oc = q4 * 4 + r;
        if (oc < 6 && pxt2 < 49) {
            float v = t2a[r] + bt2[oc];
            sbuf[1176 + oc * 49 + pxt2] = v;
            score_out[b * NA + 1176 + oc * 49 + pxt2] = v;
        }
    }
    // stage wt3 (overwrites dead dh region)
    for (int i = tid; i < 1152; i += 256) wt3s[i] = wt3[i];
    __syncthreads();

    // ================= phase C: t3 (VALU) + anchor staging =================
    if (tid < 144) {
        int oc = tid >> 4, px = tid & 15;
        float s = bt3[oc];
        for (int ic = 0; ic < 128; ++ic) s += wt3s[oc * 128 + ic] * d3f[ic * 16 + px];
        sbuf[1470 + oc * 16 + px] = s;
        score_out[b * NA + 1470 + oc * 16 + px] = s;
    }
    for (int j = tid; j < NA; j += 256) {
        int4 a = ((const int4*)anchors)[j];
        float a0 = (float)a.x, a1 = (float)a.y, a2 = (float)a.z, a3 = (float)a.w;
        y0s[j] = a0; x0s[j] = a1; y1s[j] = a2; x1s[j] = a3;
        ars[j] = (a2 - a0) * (a3 - a1);
    }
    __syncthreads();

    // ================= phase D: greedy hard-NMS top-4 =================
    for (int it = 0; it < TOPN; ++it) {
        float bv = -INFINITY; int bi = NA;
        for (int j = tid; j < NA; j += 256) {
            float v = sbuf[j];
            if (v > bv || (v == bv && j < bi)) { bv = v; bi = j; }
        }
        rv[tid] = bv; ri[tid] = bi;
        __syncthreads();
        for (int off = 128; off > 0; off >>= 1) {
            if (tid < off) {
                float ov = rv[tid + off]; int oi = ri[tid + off];
                if (ov > rv[tid] || (ov == rv[tid] && oi < ri[tid])) { rv[tid] = ov; ri[tid] = oi; }
            }
            __syncthreads();
        }
        int K = ri[0]; float V = rv[0];
        if (tid == 0) {
            out_idx[b * TOPN + it] = (float)K;
            out_prob[b * TOPN + it] = V;
            idx_ws[b * TOPN + it] = K;
        }
        float ky0 = y0s[K], kx0 = x0s[K], ky1 = y1s[K], kx1 = x1s[K], ka = ars[K];
        for (int j = tid; j < NA; j += 256) {
            float iy = fmaxf(fminf(y1s[j], ky1) - fmaxf(y0s[j], ky0), 0.f);
            float ix = fmaxf(fminf(x1s[j], kx1) - fmaxf(x0s[j], kx0), 0.f);
            float inter = iy * ix;
            float iou = inter / (ars[j] + ka - inter);
            if (iou >= 0.25f) sbuf[j] = -INFINITY;
        }
        __syncthreads();
    }
}

// ---------------- bilinear crop-resize ----------------
__global__ __launch_bounds__(256) void k_crop(const float* __restrict__ x,
                                              const int* __restrict__ anchors,
                                              const int* __restrict__ idx_ws,
                                              float* __restrict__ out) {
    int blk = blockIdx.x;
    int crop = blk / OUTS;
    int i = blk % OUTS;
    int j = threadIdx.x;
    if (j >= OUTS) return;
    int b = crop >> 2;
    int a = idx_ws[crop];
    int y0 = anchors[a * 4], x0 = anchors[a * 4 + 1];
    int y1 = anchors[a * 4 + 2], x1 = anchors[a * 4 + 3];

    float ti = (float)i / 223.f;
    float ys = (float)y0 + ti * (float)(y1 - y0 - 1);
    int yi0 = (int)ys;
    int yi1 = min(yi0 + 1, HP - 1);
    float wy = ys - (float)yi0;

    float tj = (float)j / 223.f;
    float xs = (float)x0 + tj * (float)(x1 - x0 - 1);
    int xi0 = (int)xs;
    int xi1 = min(xi0 + 1, HP - 1);
    float wx = xs - (float)xi0;

    int ry0 = yi0 - PADW, ry1 = yi1 - PADW, rx0 = xi0 - PADW, rx1 = xi1 - PADW;
    bool vy0 = (ry0 >= 0) && (ry0 < IM), vy1 = (ry1 >= 0) && (ry1 < IM);
    bool vx0 = (rx0 >= 0) && (rx0 < IM), vx1 = (rx1 >= 0) && (rx1 < IM);

    float w00 = (1.f - wy) * (1.f - wx), w01 = (1.f - wy) * wx;
    float w10 = wy * (1.f - wx), w11 = wy * wx;

#pragma unroll
    for (int c = 0; c < 3; ++c) {
        const float* xp = x + (size_t)(b * 3 + c) * IM * IM;
        float g00 = (vy0 && vx0) ? xp[ry0 * IM + rx0] : 0.f;
        float g01 = (vy0 && vx1) ? xp[ry0 * IM + rx1] : 0.f;
        float g10 = (vy1 && vx0) ? xp[ry1 * IM + rx0] : 0.f;
        float g11 = (vy1 && vx1) ? xp[ry1 * IM + rx1] : 0.f;
        out[(size_t)(crop * 3 + c) * OUTS * OUTS + i * OUTS + j] =
            g00 * w00 + g01 * w01 + g10 * w10 + g11 * w11;
    }
}

extern "C" void kernel_launch(void* const* d_in, const int* in_sizes, int n_in,
                              void* d_out, int out_size, void* d_ws, size_t ws_size,
                              hipStream_t stream) {
    (void)in_sizes; (void)n_in; (void)out_size; (void)ws_size;
    const float* x    = (const float*)d_in[0];
    const float* rpn  = (const float*)d_in[1];
    const float* w1   = (const float*)d_in[2];
    const float* b1   = (const float*)d_in[3];
    const float* w2   = (const float*)d_in[4];
    const float* b2   = (const float*)d_in[5];
    const float* w3   = (const float*)d_in[6];
    const float* b3   = (const float*)d_in[7];
    const float* wt1  = (const float*)d_in[8];
    const float* bt1  = (const float*)d_in[9];
    const float* wt2  = (const float*)d_in[10];
    const float* bt2  = (const float*)d_in[11];
    const float* wt3  = (const float*)d_in[12];
    const float* bt3  = (const float*)d_in[13];
    const int*   anc  = (const int*)d_in[14];

    float* out = (float*)d_out;
    float* ws  = (float*)d_ws;
    float* d1  = ws + WS_D1;
    int*   idxw = (int*)(ws + WS_IDX);
    unsigned short* w1h = (unsigned short*)(ws + WS_WT);
    unsigned short* w1l = w1h + NWT1;
    unsigned short* w2h = w1l + NWT1;
    unsigned short* w2l = w2h + NWT2;
    unsigned short* w3h = w2l + NWT2;
    unsigned short* w3l = w3h + NWT2;

    static const int TAIL_LDS = 160568;
    hipFuncSetAttribute((const void*)k_tail, hipFuncAttributeMaxDynamicSharedMemorySize, TAIL_LDS);

    k_wrepack<<<1024, 256, 0, stream>>>(w1, w1h, w1l, IC1);
    k_wrepack<<<64, 256, 0, stream>>>(w2, w2h, w2l, C128);
    k_wrepack<<<64, 256, 0, stream>>>(w3, w3h, w3l, C128);
    k_init_d1<<<(BATCH * C128 * 196 + 255) / 256, 256, 0, stream>>>(d1, b1);
    k_conv1_mfma<<<256, 256, 0, stream>>>(rpn, w1h, w1l, d1);
    k_tail<<<BATCH, 256, TAIL_LDS, stream>>>(d1, w2h, w2l, w3h, w3l, b2, b3,
                                             wt1, bt1, wt2, bt2, wt3, bt3, anc,
                                             out + OFF_SCORE, out + OFF_TOPIDX,
                                             out + OFF_TOPPROB, idxw);
    k_crop<<<BATCH * TOPN * OUTS, 256, 0, stream>>>(x, anc, idxw, out);
}

// Round 5
// 344.538 us; speedup vs baseline: 2.4015x; 1.0736x over previous
//
#include <hip/hip_runtime.h>
#include <math.h>

#define BATCH 16
#define TOPN 4
#define OUTS 224
#define PADW 224
#define IM 448
#define HP 896
#define NA 1614
#define IC1 2048
#define C128 128

// d_out float offsets
#define N_PART (BATCH*TOPN*3*OUTS*OUTS)       // 9,633,792
#define OFF_TOPIDX  (N_PART)
#define OFF_TOPPROB (N_PART + BATCH*TOPN)
#define OFF_SCORE   (N_PART + 2*BATCH*TOPN)

// ws float offsets.  d1 is [b][px 196][oc 128]
#define WS_D1 0
#define WS_IDX (BATCH*C128*196)                // 64 ints
#define WS_WT  (WS_IDX + 64)                   // repacked weights (ushort)
#define NWT1 (9*2048*128)
#define NWT2 (9*128*128)
#define NRPNT (BATCH*196*IC1)

typedef __attribute__((ext_vector_type(8))) short frag8;     // 8 bf16 (4 VGPRs)
typedef __attribute__((ext_vector_type(16))) float acc16;    // 16 fp32 acc (32x32)
typedef __attribute__((ext_vector_type(4)))  float acc4;     // 4 fp32 acc (16x16)

__device__ __forceinline__ unsigned short f2bf(float f) {
    unsigned int u = __float_as_uint(f);
    u = (u + 0x7fffu + ((u >> 16) & 1u)) >> 16;   // RNE
    return (unsigned short)u;
}
__device__ __forceinline__ float bf2f(unsigned short h) {
    return __uint_as_float(((unsigned int)h) << 16);
}
__device__ __forceinline__ void cvt4(const float* v, ushort4* h, ushort4* lo) {
    unsigned short hh[4], ll[4];
#pragma unroll
    for (int e = 0; e < 4; ++e) { hh[e] = f2bf(v[e]); ll[e] = f2bf(v[e] - bf2f(hh[e])); }
    *h  = make_ushort4(hh[0], hh[1], hh[2], hh[3]);
    *lo = make_ushort4(ll[0], ll[1], ll[2], ll[3]);
}

// ---------------- init d1 with bias (d1 layout [b][px][oc]) ----------------
__global__ void k_init_d1(float* __restrict__ d1, const float* __restrict__ b1) {
    int i = blockIdx.x * 256 + threadIdx.x;
    if (i < BATCH * C128 * 196) d1[i] = b1[i & 127];
}

// ---------------- rpn transpose: rpn[b][ic][px] fp32 -> rpnT[b][px][ic] bf16 hi/lo ------
// grid 512: blockIdx.x = icg*16 + b (icg = 64-ic group)
__global__ __launch_bounds__(256) void k_rpnT(const float* __restrict__ rpn,
                                              unsigned short* __restrict__ TH,
                                              unsigned short* __restrict__ TL) {
    __shared__ float tile[64 * 201];   // [icl][px], stride 201 (odd word stride)
    const int tid = threadIdx.x;
    const int b = blockIdx.x & 15, icg = blockIdx.x >> 4;
    const int ic0 = icg * 64;
    for (int qq = tid; qq < 3136; qq += 256) {
        int icl = qq / 49, r = qq % 49, p = r * 4;
        const float4 v = *(const float4*)&rpn[(size_t)(b * IC1 + ic0 + icl) * 196 + p];
        tile[icl * 201 + p + 0] = v.x;
        tile[icl * 201 + p + 1] = v.y;
        tile[icl * 201 + p + 2] = v.z;
        tile[icl * 201 + p + 3] = v.w;
    }
    __syncthreads();
    for (int qq = tid; qq < 3136; qq += 256) {
        int px = qq >> 4, ic4 = (qq & 15) * 4;
        float vv[4];
#pragma unroll
        for (int e = 0; e < 4; ++e) vv[e] = tile[(ic4 + e) * 201 + px];
        ushort4 h4, l4; cvt4(vv, &h4, &l4);
        size_t gi = (size_t)(b * 196 + px) * IC1 + ic0 + ic4;
        *(ushort4*)&TH[gi] = h4;
        *(ushort4*)&TL[gi] = l4;
    }
}

// ---------------- weight repack: w[oc][ic][tap] fp32 -> [tap][oc][ic] bf16 hi/lo ----------
__global__ __launch_bounds__(256) void k_wrepack(const float* __restrict__ w,
                                                 unsigned short* __restrict__ w_hi,
                                                 unsigned short* __restrict__ w_lo,
                                                 int IC) {
    int i = blockIdx.x * 256 + threadIdx.x;
    if (i >= 128 * IC) return;
    int oc = i / IC, ic = i % IC;
    const float* src = w + (size_t)(oc * IC + ic) * 9;
#pragma unroll
    for (int tap = 0; tap < 9; ++tap) {
        float v = src[tap];
        unsigned short h = f2bf(v);
        size_t gi = ((size_t)tap * 128 + oc) * IC + ic;
        w_hi[gi] = h;
        w_lo[gi] = f2bf(v - bf2f(h));
    }
}

// ---------------- conv1 via MFMA 32x32x16 bf16 (A=input px, B=weight oc) ----------------
// grid 256: blockIdx.x = kg*16 + b; block 512 thr = 8 waves
// wave w: mtw=w&3 -> M-pair {2mtw,2mtw+1} (px tiles of 32, 196 pad 256);
//         ntw=w>>2 -> N-pair {2ntw,2ntw+1} (oc tiles of 32)
__global__ __launch_bounds__(512, 1) void k_conv1_mfma(const unsigned short* __restrict__ rpnTH,
                                                       const unsigned short* __restrict__ rpnTL,
                                                       const unsigned short* __restrict__ wt_hi,
                                                       const unsigned short* __restrict__ wt_lo,
                                                       float* __restrict__ d1) {
    __shared__ unsigned short inH[304 * 72];   // [pos][ic64]
    __shared__ unsigned short inL[304 * 72];
    __shared__ unsigned short wHs[128 * 72];   // [oc][ic64]
    __shared__ unsigned short wLs[128 * 72];

    const int tid = threadIdx.x;
    const int b = blockIdx.x & 15, kg = blockIdx.x >> 4;
    const int l = tid & 63, w = tid >> 6;
    const int ln = l & 31, q = l >> 5;
    const int mtw = w & 3, ntw = w >> 2;

    for (int i = tid; i < 304 * 72; i += 512) { inH[i] = 0; inL[i] = 0; }

    acc16 acc[2][2];
#pragma unroll
    for (int mt = 0; mt < 2; ++mt)
#pragma unroll
        for (int nt = 0; nt < 2; ++nt)
#pragma unroll
            for (int r = 0; r < 16; ++r) acc[mt][nt][r] = 0.f;

    int posa[2];
#pragma unroll
    for (int mt = 0; mt < 2; ++mt) {
        int px = (mtw * 2 + mt) * 32 + ln;
        posa[mt] = (px < 196) ? ((px / 14) * 16 + (px % 14)) : 256;  // 256 -> zero region
    }
    __syncthreads();

    for (int half = 0; half < 2; ++half) {
        const int ics = kg * 128 + half * 64;
        // stage input from rpnT (vector copy, conflict-free)
        for (int qq = tid; qq < 3136; qq += 512) {
            int px = qq >> 4, ic4 = (qq & 15) * 4;
            size_t gi = (size_t)(b * 196 + px) * IC1 + ics + ic4;
            ushort4 h4 = *(const ushort4*)&rpnTH[gi];
            ushort4 l4 = *(const ushort4*)&rpnTL[gi];
            int pos = (px / 14 + 1) * 16 + (px % 14 + 1);
            *(ushort4*)&inH[pos * 72 + ic4] = h4;
            *(ushort4*)&inL[pos * 72 + ic4] = l4;
        }
        // prefetch tap-0 weights into registers
        ushort4 pwh[4], pwl[4];
#pragma unroll
        for (int it = 0; it < 4; ++it) {
            int qq = tid + it * 512;
            int oc = qq >> 4, ic4 = (qq & 15) * 4;
            size_t gi = ((size_t)(0 * 128 + oc)) * IC1 + ics + ic4;
            pwh[it] = *(const ushort4*)&wt_hi[gi];
            pwl[it] = *(const ushort4*)&wt_lo[gi];
        }
        __syncthreads();

        for (int tap = 0; tap < 9; ++tap) {
            // store prefetched weights to LDS
#pragma unroll
            for (int it = 0; it < 4; ++it) {
                int qq = tid + it * 512;
                int oc = qq >> 4, ic4 = (qq & 15) * 4;
                *(ushort4*)&wHs[oc * 72 + ic4] = pwh[it];
                *(ushort4*)&wLs[oc * 72 + ic4] = pwl[it];
            }
            // prefetch next tap while this tap computes
            if (tap < 8) {
#pragma unroll
                for (int it = 0; it < 4; ++it) {
                    int qq = tid + it * 512;
                    int oc = qq >> 4, ic4 = (qq & 15) * 4;
                    size_t gi = ((size_t)((tap + 1) * 128 + oc)) * IC1 + ics + ic4;
                    pwh[it] = *(const ushort4*)&wt_hi[gi];
                    pwl[it] = *(const ushort4*)&wt_lo[gi];
                }
            }
            __syncthreads();

            const int off = (tap / 3) * 16 + (tap % 3);
#pragma unroll
            for (int c = 0; c < 4; ++c) {
                const int ko = c * 16 + q * 8;
                frag8 aH[2], aL[2], bH[2], bL[2];
#pragma unroll
                for (int mt = 0; mt < 2; ++mt) {
                    int pp = (posa[mt] + off) * 72 + ko;
                    aH[mt] = *(const frag8*)&inH[pp];
                    aL[mt] = *(const frag8*)&inL[pp];
                }
#pragma unroll
                for (int nt = 0; nt < 2; ++nt) {
                    int oc = (ntw * 2 + nt) * 32 + ln;
                    bH[nt] = *(const frag8*)&wHs[oc * 72 + ko];
                    bL[nt] = *(const frag8*)&wLs[oc * 72 + ko];
                }
#pragma unroll
                for (int mt = 0; mt < 2; ++mt)
#pragma unroll
                    for (int nt = 0; nt < 2; ++nt) {
                        acc[mt][nt] = __builtin_amdgcn_mfma_f32_32x32x16_bf16(aH[mt], bH[nt], acc[mt][nt], 0, 0, 0);
                        acc[mt][nt] = __builtin_amdgcn_mfma_f32_32x32x16_bf16(aH[mt], bL[nt], acc[mt][nt], 0, 0, 0);
                        acc[mt][nt] = __builtin_amdgcn_mfma_f32_32x32x16_bf16(aL[mt], bH[nt], acc[mt][nt], 0, 0, 0);
                    }
            }
            __syncthreads();
        }
    }

    // epilogue: C row = px, col = oc -> coalesced atomics on d1[b][px][oc]
#pragma unroll
    for (int mt = 0; mt < 2; ++mt)
#pragma unroll
        for (int nt = 0; nt < 2; ++nt) {
            int oc = (ntw * 2 + nt) * 32 + ln;
#pragma unroll
            for (int r = 0; r < 16; ++r) {
                int m = (r & 3) + 8 * (r >> 2) + 4 * q;
                int px = (mtw * 2 + mt) * 32 + m;
                if (px < 196)
                    atomicAdd(&d1[(size_t)(b * 196 + px) * 128 + oc], acc[mt][nt][r]);
            }
        }
}

// ---------------- fused tail: conv2 + conv3 + tidy1/2/3 + NMS, one block per batch ----------
__global__ __launch_bounds__(256, 1) void k_tail(
    const float* __restrict__ d1,
    const unsigned short* __restrict__ w2h, const unsigned short* __restrict__ w2l,
    const unsigned short* __restrict__ w3h, const unsigned short* __restrict__ w3l,
    const float* __restrict__ b2, const float* __restrict__ b3,
    const float* __restrict__ wt1, const float* __restrict__ bt1,
    const float* __restrict__ wt2, const float* __restrict__ bt2,
    const float* __restrict__ wt3, const float* __restrict__ bt3,
    const int* __restrict__ anchors,
    float* __restrict__ score_out, float* __restrict__ out_idx,
    float* __restrict__ out_prob, int* __restrict__ idx_ws) {
    extern __shared__ char smem[];
    unsigned short* inH = (unsigned short*)(smem);            // [pos 304][ic 72]
    unsigned short* inL = (unsigned short*)(smem + 43776);
    unsigned short* wHs = (unsigned short*)(smem + 87552);    // [oc 128][ic 72]
    unsigned short* wLs = (unsigned short*)(smem + 105984);
    unsigned short* t1H = (unsigned short*)(smem + 124416);   // [oc16][ic 72]
    unsigned short* t1L = (unsigned short*)(smem + 126720);
    float*  d2f  = (float*)(smem + 129024);                   // [px 49][oc 128]
    float*  sbuf = (float*)(smem + 154112);                   // [1614]
    unsigned short* dhH = (unsigned short*)(smem);            // [pos 192][ic 72]
    unsigned short* dhL = (unsigned short*)(smem + 27648);
    float*  d3f  = (float*)(smem + 55296);                    // [ic 128][px 16]
    unsigned short* t2H = (unsigned short*)(smem + 63488);
    unsigned short* t2L = (unsigned short*)(smem + 65792);
    unsigned short* w3H = (unsigned short*)(smem + 68096);
    unsigned short* w3L = (unsigned short*)(smem + 86528);
    float* wt3s = (float*)(smem);
    float* y0s = (float*)(smem + 6464);
    float* x0s = (float*)(smem + 12928);
    float* y1s = (float*)(smem + 19392);
    float* x1s = (float*)(smem + 25856);
    float* ars = (float*)(smem + 32320);
    float* rv  = (float*)(smem + 38784);
    int*   ri  = (int*)(smem + 39808);

    const int tid = threadIdx.x;
    const int b = blockIdx.x;
    const int l = tid & 63, w = tid >> 6;
    const int ln = l & 31, q = l >> 5;
    const int l16 = l & 15, q4 = l >> 4;

    // ================= phase A: conv2 + t1 =================
    for (int i = tid; i < 304 * 72; i += 256) { inH[i] = 0; inL[i] = 0; }

    acc16 c2[2];
    acc4 t1a[4];
#pragma unroll
    for (int nt = 0; nt < 2; ++nt)
#pragma unroll
        for (int r = 0; r < 16; ++r) c2[nt][r] = 0.f;
#pragma unroll
    for (int i = 0; i < 4; ++i)
#pragma unroll
        for (int r = 0; r < 4; ++r) t1a[i][r] = 0.f;

    const int mtw = w & 1, ntw = w >> 1;
    int posa2;
    {
        int px = mtw * 32 + ln;
        posa2 = (px < 49) ? ((px / 7) * 32 + (px % 7) * 2) : 256;
    }
    __syncthreads();

    for (int half = 0; half < 2; ++half) {
        const int ics = half * 64;
        for (int qq = tid; qq < 3136; qq += 256) {
            int px = qq >> 4, ic4 = (qq & 15) * 4;
            float4 v = *(const float4*)&d1[(size_t)(b * 196 + px) * 128 + ics + ic4];
            float vv[4] = {fmaxf(v.x, 0.f), fmaxf(v.y, 0.f), fmaxf(v.z, 0.f), fmaxf(v.w, 0.f)};
            ushort4 h4, l4; cvt4(vv, &h4, &l4);
            int pos = (px / 14 + 1) * 16 + (px % 14 + 1);
            *(ushort4*)&inH[pos * 72 + ic4] = h4;
            *(ushort4*)&inL[pos * 72 + ic4] = l4;
        }
        for (int qq = tid; qq < 1024; qq += 256) {
            int m = qq >> 6, k = qq & 63;
            float v = (m < 6) ? wt1[m * 128 + ics + k] : 0.f;
            unsigned short h = f2bf(v);
            t1H[m * 72 + k] = h;
            t1L[m * 72 + k] = f2bf(v - bf2f(h));
        }
        __syncthreads();

        for (int tap = 0; tap < 9; ++tap) {
            for (int qq = tid; qq < 2048; qq += 256) {
                int oc = qq >> 4, ic4 = (qq & 15) * 4;
                size_t gi = ((size_t)tap * 128 + oc) * C128 + ics + ic4;
                *(ushort4*)&wHs[oc * 72 + ic4] = *(const ushort4*)&w2h[gi];
                *(ushort4*)&wLs[oc * 72 + ic4] = *(const ushort4*)&w2l[gi];
            }
            __syncthreads();
            const int off = (tap / 3) * 16 + (tap % 3);
#pragma unroll
            for (int c = 0; c < 4; ++c) {
                const int ko = c * 16 + q * 8;
                int pp = (posa2 + off) * 72 + ko;
                frag8 aH = *(const frag8*)&inH[pp];
                frag8 aL = *(const frag8*)&inL[pp];
#pragma unroll
                for (int nt = 0; nt < 2; ++nt) {
                    int oc = (ntw * 2 + nt) * 32 + ln;
                    frag8 bH = *(const frag8*)&wHs[oc * 72 + ko];
                    frag8 bL = *(const frag8*)&wLs[oc * 72 + ko];
                    c2[nt] = __builtin_amdgcn_mfma_f32_32x32x16_bf16(aH, bH, c2[nt], 0, 0, 0);
                    c2[nt] = __builtin_amdgcn_mfma_f32_32x32x16_bf16(aH, bL, c2[nt], 0, 0, 0);
                    c2[nt] = __builtin_amdgcn_mfma_f32_32x32x16_bf16(aL, bH, c2[nt], 0, 0, 0);
                }
            }
            __syncthreads();
        }

#pragma unroll
        for (int i = 0; i < 4; ++i) {
            int px = (w * 4 + i) * 16 + l16;
            int pos = (px < 196) ? ((px / 14 + 1) * 16 + (px % 14 + 1)) : 256;
#pragma unroll
            for (int c = 0; c < 2; ++c) {
                int ko = c * 32 + q4 * 8;
                frag8 aH = *(const frag8*)&t1H[l16 * 72 + ko];
                frag8 aL = *(const frag8*)&t1L[l16 * 72 + ko];
                frag8 bH = *(const frag8*)&inH[pos * 72 + ko];
                frag8 bL = *(const frag8*)&inL[pos * 72 + ko];
                t1a[i] = __builtin_amdgcn_mfma_f32_16x16x32_bf16(aH, bH, t1a[i], 0, 0, 0);
                t1a[i] = __builtin_amdgcn_mfma_f32_16x16x32_bf16(aH, bL, t1a[i], 0, 0, 0);
                t1a[i] = __builtin_amdgcn_mfma_f32_16x16x32_bf16(aL, bH, t1a[i], 0, 0, 0);
            }
        }
        __syncthreads();
    }

#pragma unroll
    for (int nt = 0; nt < 2; ++nt) {
        int oc = (ntw * 2 + nt) * 32 + ln;
        float bias = b2[oc];
#pragma unroll
        for (int r = 0; r < 16; ++r) {
            int m = (r & 3) + 8 * (r >> 2) + 4 * q;
            int px = mtw * 32 + m;
            if (px < 49) d2f[px * 128 + oc] = fmaxf(c2[nt][r] + bias, 0.f);
        }
    }
#pragma unroll
    for (int i = 0; i < 4; ++i) {
        int px = (w * 4 + i) * 16 + l16;
#pragma unroll
        for (int r = 0; r < 4; ++r) {
            int oc = q4 * 4 + r;
            if (oc < 6 && px < 196) {
                float v = t1a[i][r] + bt1[oc];
                sbuf[oc * 196 + px] = v;
                score_out[b * NA + oc * 196 + px] = v;
            }
        }
    }
    __syncthreads();

    // ================= phase B: conv3 + t2 =================
    for (int i = tid; i < 192 * 72; i += 256) { dhH[i] = 0; dhL[i] = 0; }

    acc16 c3;
    acc4 t2a;
#pragma unroll
    for (int r = 0; r < 16; ++r) c3[r] = 0.f;
#pragma unroll
    for (int r = 0; r < 4; ++r) t2a[r] = 0.f;

    const int posb3 = (ln < 16) ? ((ln / 4) * 32 + (ln % 4) * 2) : 144;
    const int pxt2 = w * 16 + l16;
    const int posbt2 = (pxt2 < 49) ? ((pxt2 / 7 + 1) * 16 + (pxt2 % 7 + 1)) : 144;
    __syncthreads();

    for (int half = 0; half < 2; ++half) {
        const int ics = half * 64;
        for (int qq = tid; qq < 784; qq += 256) {
            int px = qq >> 4, ic4 = (qq & 15) * 4;
            float4 v = *(const float4*)&d2f[px * 128 + ics + ic4];
            float vv[4] = {v.x, v.y, v.z, v.w};
            ushort4 h4, l4; cvt4(vv, &h4, &l4);
            int pos = (px / 7 + 1) * 16 + (px % 7 + 1);
            *(ushort4*)&dhH[pos * 72 + ic4] = h4;
            *(ushort4*)&dhL[pos * 72 + ic4] = l4;
        }
        for (int qq = tid; qq < 1024; qq += 256) {
            int m = qq >> 6, k = qq & 63;
            float v = (m < 6) ? wt2[m * 128 + ics + k] : 0.f;
            unsigned short h = f2bf(v);
            t2H[m * 72 + k] = h;
            t2L[m * 72 + k] = f2bf(v - bf2f(h));
        }
        __syncthreads();

        for (int tap = 0; tap < 9; ++tap) {
            for (int qq = tid; qq < 2048; qq += 256) {
                int oc = qq >> 4, ic4 = (qq & 15) * 4;
                size_t gi = ((size_t)tap * 128 + oc) * C128 + ics + ic4;
                *(ushort4*)&w3H[oc * 72 + ic4] = *(const ushort4*)&w3h[gi];
                *(ushort4*)&w3L[oc * 72 + ic4] = *(const ushort4*)&w3l[gi];
            }
            __syncthreads();
            const int off = (tap / 3) * 16 + (tap % 3);
#pragma unroll
            for (int c = 0; c < 4; ++c) {
                const int ko = c * 16 + q * 8;
                int pp = (posb3 + off) * 72 + ko;
                frag8 aH = *(const frag8*)&dhH[pp];
                frag8 aL = *(const frag8*)&dhL[pp];
                int oc = w * 32 + ln;
                frag8 bH = *(const frag8*)&w3H[oc * 72 + ko];
                frag8 bL = *(const frag8*)&w3L[oc * 72 + ko];
                c3 = __builtin_amdgcn_mfma_f32_32x32x16_bf16(aH, bH, c3, 0, 0, 0);
                c3 = __builtin_amdgcn_mfma_f32_32x32x16_bf16(aH, bL, c3, 0, 0, 0);
                c3 = __builtin_amdgcn_mfma_f32_32x32x16_bf16(aL, bH, c3, 0, 0, 0);
            }
            __syncthreads();
        }

#pragma unroll
        for (int c = 0; c < 2; ++c) {
            int ko = c * 32 + q4 * 8;
            frag8 aH = *(const frag8*)&t2H[l16 * 72 + ko];
            frag8 aL = *(const frag8*)&t2L[l16 * 72 + ko];
            frag8 bH = *(const frag8*)&dhH[posbt2 * 72 + ko];
            frag8 bL = *(const frag8*)&dhL[posbt2 * 72 + ko];
            t2a = __builtin_amdgcn_mfma_f32_16x16x32_bf16(aH, bH, t2a, 0, 0, 0);
            t2a = __builtin_amdgcn_mfma_f32_16x16x32_bf16(aH, bL, t2a, 0, 0, 0);
            t2a = __builtin_amdgcn_mfma_f32_16x16x32_bf16(aL, bH, t2a, 0, 0, 0);
        }
        __syncthreads();
    }

    {
        int oc = w * 32 + ln;
        float bias = b3[oc];
#pragma unroll
        for (int r = 0; r < 16; ++r) {
            int px = (r & 3) + 8 * (r >> 2) + 4 * q;
            if (px < 16) d3f[oc * 16 + px] = fmaxf(c3[r] + bias, 0.f);
        }
    }
#pragma unroll
    for (int r = 0; r < 4; ++r) {
        int oc = q4 * 4 + r;
        if (oc < 6 && pxt2 < 49) {
            float v = t2a[r] + bt2[oc];
            sbuf[1176 + oc * 49 + pxt2] = v;
            score_out[b * NA + 1176 + oc * 49 + pxt2] = v;
        }
    }
    for (int i = tid; i < 1152; i += 256) wt3s[i] = wt3[i];
    __syncthreads();

    // ================= phase C: t3 (VALU) + anchor staging =================
    if (tid < 144) {
        int oc = tid >> 4, px = tid & 15;
        float s = bt3[oc];
        for (int ic = 0; ic < 128; ++ic) s += wt3s[oc * 128 + ic] * d3f[ic * 16 + px];
        sbuf[1470 + oc * 16 + px] = s;
        score_out[b * NA + 1470 + oc * 16 + px] = s;
    }
    for (int j = tid; j < NA; j += 256) {
        int4 a = ((const int4*)anchors)[j];
        float a0 = (float)a.x, a1 = (float)a.y, a2 = (float)a.z, a3 = (float)a.w;
        y0s[j] = a0; x0s[j] = a1; y1s[j] = a2; x1s[j] = a3;
        ars[j] = (a2 - a0) * (a3 - a1);
    }
    __syncthreads();

    // ================= phase D: greedy hard-NMS top-4 =================
    for (int it = 0; it < TOPN; ++it) {
        float bv = -INFINITY; int bi = NA;
        for (int j = tid; j < NA; j += 256) {
            float v = sbuf[j];
            if (v > bv || (v == bv && j < bi)) { bv = v; bi = j; }
        }
        rv[tid] = bv; ri[tid] = bi;
        __syncthreads();
        for (int off = 128; off > 0; off >>= 1) {
            if (tid < off) {
                float ov = rv[tid + off]; int oi = ri[tid + off];
                if (ov > rv[tid] || (ov == rv[tid] && oi < ri[tid])) { rv[tid] = ov; ri[tid] = oi; }
            }
            __syncthreads();
        }
        int K = ri[0]; float V = rv[0];
        if (tid == 0) {
            out_idx[b * TOPN + it] = (float)K;
            out_prob[b * TOPN + it] = V;
            idx_ws[b * TOPN + it] = K;
        }
        float ky0 = y0s[K], kx0 = x0s[K], ky1 = y1s[K], kx1 = x1s[K], ka = ars[K];
        for (int j = tid; j < NA; j += 256) {
            float iy = fmaxf(fminf(y1s[j], ky1) - fmaxf(y0s[j], ky0), 0.f);
            float ix = fmaxf(fminf(x1s[j], kx1) - fmaxf(x0s[j], kx0), 0.f);
            float inter = iy * ix;
            float iou = inter / (ars[j] + ka - inter);
            if (iou >= 0.25f) sbuf[j] = -INFINITY;
        }
        __syncthreads();
    }
}

// ---------------- bilinear crop-resize ----------------
__global__ __launch_bounds__(256) void k_crop(const float* __restrict__ x,
                                              const int* __restrict__ anchors,
                                              const int* __restrict__ idx_ws,
                                              float* __restrict__ out) {
    int blk = blockIdx.x;
    int crop = blk / OUTS;
    int i = blk % OUTS;
    int j = threadIdx.x;
    if (j >= OUTS) return;
    int b = crop >> 2;
    int a = idx_ws[crop];
    int y0 = anchors[a * 4], x0 = anchors[a * 4 + 1];
    int y1 = anchors[a * 4 + 2], x1 = anchors[a * 4 + 3];

    float ti = (float)i / 223.f;
    float ys = (float)y0 + ti * (float)(y1 - y0 - 1);
    int yi0 = (int)ys;
    int yi1 = min(yi0 + 1, HP - 1);
    float wy = ys - (float)yi0;

    float tj = (float)j / 223.f;
    float xs = (float)x0 + tj * (float)(x1 - x0 - 1);
    int xi0 = (int)xs;
    int xi1 = min(xi0 + 1, HP - 1);
    float wx = xs - (float)xi0;

    int ry0 = yi0 - PADW, ry1 = yi1 - PADW, rx0 = xi0 - PADW, rx1 = xi1 - PADW;
    bool vy0 = (ry0 >= 0) && (ry0 < IM), vy1 = (ry1 >= 0) && (ry1 < IM);
    bool vx0 = (rx0 >= 0) && (rx0 < IM), vx1 = (rx1 >= 0) && (rx1 < IM);

    float w00 = (1.f - wy) * (1.f - wx), w01 = (1.f - wy) * wx;
    float w10 = wy * (1.f - wx), w11 = wy * wx;

#pragma unroll
    for (int c = 0; c < 3; ++c) {
        const float* xp = x + (size_t)(b * 3 + c) * IM * IM;
        float g00 = (vy0 && vx0) ? xp[ry0 * IM + rx0] : 0.f;
        float g01 = (vy0 && vx1) ? xp[ry0 * IM + rx1] : 0.f;
        float g10 = (vy1 && vx0) ? xp[ry1 * IM + rx0] : 0.f;
        float g11 = (vy1 && vx1) ? xp[ry1 * IM + rx1] : 0.f;
        out[(size_t)(crop * 3 + c) * OUTS * OUTS + i * OUTS + j] =
            g00 * w00 + g01 * w01 + g10 * w10 + g11 * w11;
    }
}

extern "C" void kernel_launch(void* const* d_in, const int* in_sizes, int n_in,
                              void* d_out, int out_size, void* d_ws, size_t ws_size,
                              hipStream_t stream) {
    (void)in_sizes; (void)n_in; (void)out_size; (void)ws_size;
    const float* x    = (const float*)d_in[0];
    const float* rpn  = (const float*)d_in[1];
    const float* w1   = (const float*)d_in[2];
    const float* b1   = (const float*)d_in[3];
    const float* w2   = (const float*)d_in[4];
    const float* b2   = (const float*)d_in[5];
    const float* w3   = (const float*)d_in[6];
    const float* b3   = (const float*)d_in[7];
    const float* wt1  = (const float*)d_in[8];
    const float* bt1  = (const float*)d_in[9];
    const float* wt2  = (const float*)d_in[10];
    const float* bt2  = (const float*)d_in[11];
    const float* wt3  = (const float*)d_in[12];
    const float* bt3  = (const float*)d_in[13];
    const int*   anc  = (const int*)d_in[14];

    float* out = (float*)d_out;
    float* ws  = (float*)d_ws;
    float* d1  = ws + WS_D1;
    int*   idxw = (int*)(ws + WS_IDX);
    unsigned short* w1h = (unsigned short*)(ws + WS_WT);
    unsigned short* w1l = w1h + NWT1;
    unsigned short* w2h = w1l + NWT1;
    unsigned short* w2l = w2h + NWT2;
    unsigned short* w3h = w2l + NWT2;
    unsigned short* w3l = w3h + NWT2;
    unsigned short* rpnTH = w3l + NWT2;
    unsigned short* rpnTL = rpnTH + NRPNT;

    static const int TAIL_LDS = 160568;
    hipFuncSetAttribute((const void*)k_tail, hipFuncAttributeMaxDynamicSharedMemorySize, TAIL_LDS);

    k_wrepack<<<1024, 256, 0, stream>>>(w1, w1h, w1l, IC1);
    k_wrepack<<<64, 256, 0, stream>>>(w2, w2h, w2l, C128);
    k_wrepack<<<64, 256, 0, stream>>>(w3, w3h, w3l, C128);
    k_rpnT<<<512, 256, 0, stream>>>(rpn, rpnTH, rpnTL);
    k_init_d1<<<(BATCH * C128 * 196 + 255) / 256, 256, 0, stream>>>(d1, b1);
    k_conv1_mfma<<<256, 512, 0, stream>>>(rpnTH, rpnTL, w1h, w1l, d1);
    k_tail<<<BATCH, 256, TAIL_LDS, stream>>>(d1, w2h, w2l, w3h, w3l, b2, b3,
                                             wt1, bt1, wt2, bt2, wt3, bt3, anc,
                                             out + OFF_SCORE, out + OFF_TOPIDX,
                                             out + OFF_TOPPROB, idxw);
    k_crop<<<BATCH * TOPN * OUTS, 256, 0, stream>>>(x, anc, idxw, out);
}

// Round 6
// 287.116 us; speedup vs baseline: 2.8818x; 1.2000x over previous
//
#include <hip/hip_runtime.h>
#include <math.h>

#define BATCH 16
#define TOPN 4
#define OUTS 224
#define PADW 224
#define IM 448
#define HP 896
#define NA 1614
#define IC1 2048
#define C128 128

// d_out float offsets
#define N_PART (BATCH*TOPN*3*OUTS*OUTS)       // 9,633,792
#define OFF_TOPIDX  (N_PART)
#define OFF_TOPPROB (N_PART + BATCH*TOPN)
#define OFF_SCORE   (N_PART + 2*BATCH*TOPN)

// ws float offsets.  d1 is [b][px 196][oc 128]
#define WS_D1 0
#define WS_IDX (BATCH*C128*196)                // 64 ints
#define WS_WT  (WS_IDX + 64)                   // repacked weights (ushort)
#define NWT1 (9*2048*128)
#define NWT2 (9*128*128)
#define NRPNT (BATCH*196*IC1)

typedef __attribute__((ext_vector_type(8))) short frag8;     // 8 bf16 (4 VGPRs)
typedef __attribute__((ext_vector_type(16))) float acc16;    // 16 fp32 acc (32x32)
typedef __attribute__((ext_vector_type(4)))  float acc4;     // 4 fp32 acc (16x16)

__device__ __forceinline__ unsigned short f2bf(float f) {
    unsigned int u = __float_as_uint(f);
    u = (u + 0x7fffu + ((u >> 16) & 1u)) >> 16;   // RNE
    return (unsigned short)u;
}
__device__ __forceinline__ float bf2f(unsigned short h) {
    return __uint_as_float(((unsigned int)h) << 16);
}
__device__ __forceinline__ void cvt4(const float* v, ushort4* h, ushort4* lo) {
    unsigned short hh[4], ll[4];
#pragma unroll
    for (int e = 0; e < 4; ++e) { hh[e] = f2bf(v[e]); ll[e] = f2bf(v[e] - bf2f(hh[e])); }
    *h  = make_ushort4(hh[0], hh[1], hh[2], hh[3]);
    *lo = make_ushort4(ll[0], ll[1], ll[2], ll[3]);
}

// ---------------- fused prep: wrepack(w1,w2,w3) + rpn transpose + init d1 ----------------
__device__ __forceinline__ void wrepack_body(const float* __restrict__ w,
                                             unsigned short* __restrict__ w_hi,
                                             unsigned short* __restrict__ w_lo,
                                             int IC, int i) {
    if (i >= 128 * IC) return;
    int oc = i / IC, ic = i % IC;
    const float* src = w + (size_t)(oc * IC + ic) * 9;
#pragma unroll
    for (int tap = 0; tap < 9; ++tap) {
        float v = src[tap];
        unsigned short h = f2bf(v);
        size_t gi = ((size_t)tap * 128 + oc) * IC + ic;
        w_hi[gi] = h;
        w_lo[gi] = f2bf(v - bf2f(h));
    }
}

// grid 3232: [0,1024) w1 | [1024,1088) w2 | [1088,1152) w3 | [1152,1664) rpnT | [1664,3232) init_d1
__global__ __launch_bounds__(256) void k_prep(
    const float* __restrict__ w1, unsigned short* __restrict__ w1h, unsigned short* __restrict__ w1l,
    const float* __restrict__ w2, unsigned short* __restrict__ w2h, unsigned short* __restrict__ w2l,
    const float* __restrict__ w3, unsigned short* __restrict__ w3h, unsigned short* __restrict__ w3l,
    const float* __restrict__ rpn, unsigned short* __restrict__ TH, unsigned short* __restrict__ TL,
    const float* __restrict__ b1, float* __restrict__ d1) {
    __shared__ float tile[64 * 201];
    const int tid = threadIdx.x;
    const int blk = blockIdx.x;
    if (blk < 1024) {
        wrepack_body(w1, w1h, w1l, IC1, blk * 256 + tid);
    } else if (blk < 1088) {
        wrepack_body(w2, w2h, w2l, C128, (blk - 1024) * 256 + tid);
    } else if (blk < 1152) {
        wrepack_body(w3, w3h, w3l, C128, (blk - 1088) * 256 + tid);
    } else if (blk < 1664) {
        const int bb = blk - 1152;
        const int b = bb & 15, icg = bb >> 4;
        const int ic0 = icg * 64;
        for (int qq = tid; qq < 3136; qq += 256) {
            int icl = qq / 49, r = qq % 49, p = r * 4;
            const float4 v = *(const float4*)&rpn[(size_t)(b * IC1 + ic0 + icl) * 196 + p];
            tile[icl * 201 + p + 0] = v.x;
            tile[icl * 201 + p + 1] = v.y;
            tile[icl * 201 + p + 2] = v.z;
            tile[icl * 201 + p + 3] = v.w;
        }
        __syncthreads();
        for (int qq = tid; qq < 3136; qq += 256) {
            int px = qq >> 4, ic4 = (qq & 15) * 4;
            float vv[4];
#pragma unroll
            for (int e = 0; e < 4; ++e) vv[e] = tile[(ic4 + e) * 201 + px];
            ushort4 h4, l4; cvt4(vv, &h4, &l4);
            size_t gi = (size_t)(b * 196 + px) * IC1 + ic0 + ic4;
            *(ushort4*)&TH[gi] = h4;
            *(ushort4*)&TL[gi] = l4;
        }
    } else {
        int i = (blk - 1664) * 256 + tid;
        if (i < BATCH * C128 * 196) d1[i] = b1[i & 127];
    }
}

// ---------------- conv1 via MFMA 32x32x16 bf16 (A=input px, B=weight oc) ----------------
__global__ __launch_bounds__(512, 1) void k_conv1_mfma(const unsigned short* __restrict__ rpnTH,
                                                       const unsigned short* __restrict__ rpnTL,
                                                       const unsigned short* __restrict__ wt_hi,
                                                       const unsigned short* __restrict__ wt_lo,
                                                       float* __restrict__ d1) {
    __shared__ unsigned short inH[304 * 72];   // [pos][ic64]
    __shared__ unsigned short inL[304 * 72];
    __shared__ unsigned short wHs[128 * 72];   // [oc][ic64]
    __shared__ unsigned short wLs[128 * 72];

    const int tid = threadIdx.x;
    const int b = blockIdx.x & 15, kg = blockIdx.x >> 4;
    const int l = tid & 63, w = tid >> 6;
    const int ln = l & 31, q = l >> 5;
    const int mtw = w & 3, ntw = w >> 2;

    for (int i = tid; i < 304 * 72; i += 512) { inH[i] = 0; inL[i] = 0; }

    acc16 acc[2][2];
#pragma unroll
    for (int mt = 0; mt < 2; ++mt)
#pragma unroll
        for (int nt = 0; nt < 2; ++nt)
#pragma unroll
            for (int r = 0; r < 16; ++r) acc[mt][nt][r] = 0.f;

    int posa[2];
#pragma unroll
    for (int mt = 0; mt < 2; ++mt) {
        int px = (mtw * 2 + mt) * 32 + ln;
        posa[mt] = (px < 196) ? ((px / 14) * 16 + (px % 14)) : 256;
    }
    __syncthreads();

    for (int half = 0; half < 2; ++half) {
        const int ics = kg * 128 + half * 64;
        for (int qq = tid; qq < 3136; qq += 512) {
            int px = qq >> 4, ic4 = (qq & 15) * 4;
            size_t gi = (size_t)(b * 196 + px) * IC1 + ics + ic4;
            ushort4 h4 = *(const ushort4*)&rpnTH[gi];
            ushort4 l4 = *(const ushort4*)&rpnTL[gi];
            int pos = (px / 14 + 1) * 16 + (px % 14 + 1);
            *(ushort4*)&inH[pos * 72 + ic4] = h4;
            *(ushort4*)&inL[pos * 72 + ic4] = l4;
        }
        ushort4 pwh[4], pwl[4];
#pragma unroll
        for (int it = 0; it < 4; ++it) {
            int qq = tid + it * 512;
            int oc = qq >> 4, ic4 = (qq & 15) * 4;
            size_t gi = ((size_t)(0 * 128 + oc)) * IC1 + ics + ic4;
            pwh[it] = *(const ushort4*)&wt_hi[gi];
            pwl[it] = *(const ushort4*)&wt_lo[gi];
        }
        __syncthreads();

        for (int tap = 0; tap < 9; ++tap) {
#pragma unroll
            for (int it = 0; it < 4; ++it) {
                int qq = tid + it * 512;
                int oc = qq >> 4, ic4 = (qq & 15) * 4;
                *(ushort4*)&wHs[oc * 72 + ic4] = pwh[it];
                *(ushort4*)&wLs[oc * 72 + ic4] = pwl[it];
            }
            if (tap < 8) {
#pragma unroll
                for (int it = 0; it < 4; ++it) {
                    int qq = tid + it * 512;
                    int oc = qq >> 4, ic4 = (qq & 15) * 4;
                    size_t gi = ((size_t)((tap + 1) * 128 + oc)) * IC1 + ics + ic4;
                    pwh[it] = *(const ushort4*)&wt_hi[gi];
                    pwl[it] = *(const ushort4*)&wt_lo[gi];
                }
            }
            __syncthreads();

            const int off = (tap / 3) * 16 + (tap % 3);
#pragma unroll
            for (int c = 0; c < 4; ++c) {
                const int ko = c * 16 + q * 8;
                frag8 aH[2], aL[2], bH[2], bL[2];
#pragma unroll
                for (int mt = 0; mt < 2; ++mt) {
                    int pp = (posa[mt] + off) * 72 + ko;
                    aH[mt] = *(const frag8*)&inH[pp];
                    aL[mt] = *(const frag8*)&inL[pp];
                }
#pragma unroll
                for (int nt = 0; nt < 2; ++nt) {
                    int oc = (ntw * 2 + nt) * 32 + ln;
                    bH[nt] = *(const frag8*)&wHs[oc * 72 + ko];
                    bL[nt] = *(const frag8*)&wLs[oc * 72 + ko];
                }
#pragma unroll
                for (int mt = 0; mt < 2; ++mt)
#pragma unroll
                    for (int nt = 0; nt < 2; ++nt) {
                        acc[mt][nt] = __builtin_amdgcn_mfma_f32_32x32x16_bf16(aH[mt], bH[nt], acc[mt][nt], 0, 0, 0);
                        acc[mt][nt] = __builtin_amdgcn_mfma_f32_32x32x16_bf16(aH[mt], bL[nt], acc[mt][nt], 0, 0, 0);
                        acc[mt][nt] = __builtin_amdgcn_mfma_f32_32x32x16_bf16(aL[mt], bH[nt], acc[mt][nt], 0, 0, 0);
                    }
            }
            __syncthreads();
        }
    }

#pragma unroll
    for (int mt = 0; mt < 2; ++mt)
#pragma unroll
        for (int nt = 0; nt < 2; ++nt) {
            int oc = (ntw * 2 + nt) * 32 + ln;
#pragma unroll
            for (int r = 0; r < 16; ++r) {
                int m = (r & 3) + 8 * (r >> 2) + 4 * q;
                int px = (mtw * 2 + mt) * 32 + m;
                if (px < 196)
                    atomicAdd(&d1[(size_t)(b * 196 + px) * 128 + oc], acc[mt][nt][r]);
            }
        }
}

// ---------------- fused tail: conv2+conv3+tidy+NMS, one 512-thread block per batch -------
__global__ __launch_bounds__(512, 1) void k_tail(
    const float* __restrict__ d1,
    const unsigned short* __restrict__ w2h, const unsigned short* __restrict__ w2l,
    const unsigned short* __restrict__ w3h, const unsigned short* __restrict__ w3l,
    const float* __restrict__ b2, const float* __restrict__ b3,
    const float* __restrict__ wt1, const float* __restrict__ bt1,
    const float* __restrict__ wt2, const float* __restrict__ bt2,
    const float* __restrict__ wt3, const float* __restrict__ bt3,
    const int* __restrict__ anchors,
    float* __restrict__ score_out, float* __restrict__ out_idx,
    float* __restrict__ out_prob, int* __restrict__ idx_ws) {
    extern __shared__ char smem[];
    unsigned short* inH = (unsigned short*)(smem);            // [pos 304][ic 72]
    unsigned short* inL = (unsigned short*)(smem + 43776);
    unsigned short* wHs = (unsigned short*)(smem + 87552);    // [oc 128][ic 72]
    unsigned short* wLs = (unsigned short*)(smem + 105984);
    unsigned short* t1H = (unsigned short*)(smem + 124416);   // [oc16][ic 72]
    unsigned short* t1L = (unsigned short*)(smem + 126720);
    float*  d2f  = (float*)(smem + 129024);                   // [px 49][oc 128]
    float*  sbuf = (float*)(smem + 154112);                   // [1614]
    unsigned short* dhH = (unsigned short*)(smem);            // [pos 192][ic 72]
    unsigned short* dhL = (unsigned short*)(smem + 27648);
    float*  d3f  = (float*)(smem + 55296);                    // [oc 128][px 16]
    unsigned short* t2H = (unsigned short*)(smem + 63488);
    unsigned short* t2L = (unsigned short*)(smem + 65792);
    unsigned short* w3H = (unsigned short*)(smem + 68096);
    unsigned short* w3L = (unsigned short*)(smem + 86528);
    float* wt3s = (float*)(smem);
    float* y0s = (float*)(smem + 6464);
    float* x0s = (float*)(smem + 12928);
    float* y1s = (float*)(smem + 19392);
    float* x1s = (float*)(smem + 25856);
    float* ars = (float*)(smem + 32320);
    float* rv  = (float*)(smem + 38784);
    int*   ri  = (int*)(smem + 39808);

    const int tid = threadIdx.x;           // 0..511, 8 waves
    const int b = blockIdx.x;
    const int l = tid & 63, w = tid >> 6;
    const int ln = l & 31, q = l >> 5;
    const int l16 = l & 15, q4 = l >> 4;

    // ================= phase A: conv2 + t1 =================
    for (int i = tid; i < 304 * 72; i += 512) { inH[i] = 0; inL[i] = 0; }

    acc16 c2;
    acc4 t1a[2];
#pragma unroll
    for (int r = 0; r < 16; ++r) c2[r] = 0.f;
#pragma unroll
    for (int i = 0; i < 2; ++i)
#pragma unroll
        for (int r = 0; r < 4; ++r) t1a[i][r] = 0.f;

    const int mtw = w & 1, ntw = w >> 1;   // 2 px-tiles x 4 oc-tiles
    int posa2;
    {
        int px = mtw * 32 + ln;
        posa2 = (px < 49) ? ((px / 7) * 32 + (px % 7) * 2) : 256;
    }
    __syncthreads();

    for (int half = 0; half < 2; ++half) {
        const int ics = half * 64;
        for (int qq = tid; qq < 3136; qq += 512) {
            int px = qq >> 4, ic4 = (qq & 15) * 4;
            float4 v = *(const float4*)&d1[(size_t)(b * 196 + px) * 128 + ics + ic4];
            float vv[4] = {fmaxf(v.x, 0.f), fmaxf(v.y, 0.f), fmaxf(v.z, 0.f), fmaxf(v.w, 0.f)};
            ushort4 h4, l4; cvt4(vv, &h4, &l4);
            int pos = (px / 14 + 1) * 16 + (px % 14 + 1);
            *(ushort4*)&inH[pos * 72 + ic4] = h4;
            *(ushort4*)&inL[pos * 72 + ic4] = l4;
        }
        for (int qq = tid; qq < 1024; qq += 512) {
            int m = qq >> 6, k = qq & 63;
            float v = (m < 6) ? wt1[m * 128 + ics + k] : 0.f;
            unsigned short h = f2bf(v);
            t1H[m * 72 + k] = h;
            t1L[m * 72 + k] = f2bf(v - bf2f(h));
        }
        // prefetch tap-0 conv2 weights
        ushort4 pwh[4], pwl[4];
#pragma unroll
        for (int it = 0; it < 4; ++it) {
            int qq = tid + it * 512;
            int oc = qq >> 4, ic4 = (qq & 15) * 4;
            size_t gi = ((size_t)(0 * 128 + oc)) * C128 + ics + ic4;
            pwh[it] = *(const ushort4*)&w2h[gi];
            pwl[it] = *(const ushort4*)&w2l[gi];
        }
        __syncthreads();

        for (int tap = 0; tap < 9; ++tap) {
#pragma unroll
            for (int it = 0; it < 4; ++it) {
                int qq = tid + it * 512;
                int oc = qq >> 4, ic4 = (qq & 15) * 4;
                *(ushort4*)&wHs[oc * 72 + ic4] = pwh[it];
                *(ushort4*)&wLs[oc * 72 + ic4] = pwl[it];
            }
            if (tap < 8) {
#pragma unroll
                for (int it = 0; it < 4; ++it) {
                    int qq = tid + it * 512;
                    int oc = qq >> 4, ic4 = (qq & 15) * 4;
                    size_t gi = ((size_t)((tap + 1) * 128 + oc)) * C128 + ics + ic4;
                    pwh[it] = *(const ushort4*)&w2h[gi];
                    pwl[it] = *(const ushort4*)&w2l[gi];
                }
            }
            __syncthreads();
            const int off = (tap / 3) * 16 + (tap % 3);
#pragma unroll
            for (int c = 0; c < 4; ++c) {
                const int ko = c * 16 + q * 8;
                int pp = (posa2 + off) * 72 + ko;
                frag8 aH = *(const frag8*)&inH[pp];
                frag8 aL = *(const frag8*)&inL[pp];
                int oc = ntw * 32 + ln;
                frag8 bH = *(const frag8*)&wHs[oc * 72 + ko];
                frag8 bL = *(const frag8*)&wLs[oc * 72 + ko];
                c2 = __builtin_amdgcn_mfma_f32_32x32x16_bf16(aH, bH, c2, 0, 0, 0);
                c2 = __builtin_amdgcn_mfma_f32_32x32x16_bf16(aH, bL, c2, 0, 0, 0);
                c2 = __builtin_amdgcn_mfma_f32_32x32x16_bf16(aL, bH, c2, 0, 0, 0);
            }
            __syncthreads();
        }

        // t1 MFMA on this half (inH intact since last barrier)
#pragma unroll
        for (int i = 0; i < 2; ++i) {
            int px = (w * 2 + i) * 16 + l16;
            int pos = (px < 196) ? ((px / 14 + 1) * 16 + (px % 14 + 1)) : 256;
#pragma unroll
            for (int c = 0; c < 2; ++c) {
                int ko = c * 32 + q4 * 8;
                frag8 aH = *(const frag8*)&t1H[l16 * 72 + ko];
                frag8 aL = *(const frag8*)&t1L[l16 * 72 + ko];
                frag8 bH = *(const frag8*)&inH[pos * 72 + ko];
                frag8 bL = *(const frag8*)&inL[pos * 72 + ko];
                t1a[i] = __builtin_amdgcn_mfma_f32_16x16x32_bf16(aH, bH, t1a[i], 0, 0, 0);
                t1a[i] = __builtin_amdgcn_mfma_f32_16x16x32_bf16(aH, bL, t1a[i], 0, 0, 0);
                t1a[i] = __builtin_amdgcn_mfma_f32_16x16x32_bf16(aL, bH, t1a[i], 0, 0, 0);
            }
        }
        __syncthreads();
    }

    // conv2 epilogue -> d2f[px][oc]
    {
        int oc = ntw * 32 + ln;
        float bias = b2[oc];
#pragma unroll
        for (int r = 0; r < 16; ++r) {
            int m = (r & 3) + 8 * (r >> 2) + 4 * q;
            int px = mtw * 32 + m;
            if (px < 49) d2f[px * 128 + oc] = fmaxf(c2[r] + bias, 0.f);
        }
    }
    // t1 epilogue -> scores
#pragma unroll
    for (int i = 0; i < 2; ++i) {
        int px = (w * 2 + i) * 16 + l16;
#pragma unroll
        for (int r = 0; r < 4; ++r) {
            int oc = q4 * 4 + r;
            if (oc < 6 && px < 196) {
                float v = t1a[i][r] + bt1[oc];
                sbuf[oc * 196 + px] = v;
                score_out[b * NA + oc * 196 + px] = v;
            }
        }
    }
    __syncthreads();

    // ================= phase B: conv3 (waves 0-3) + t2 (waves 4-7) =================
    for (int i = tid; i < 192 * 72; i += 512) { dhH[i] = 0; dhL[i] = 0; }

    acc16 c3;
    acc4 t2a;
#pragma unroll
    for (int r = 0; r < 16; ++r) c3[r] = 0.f;
#pragma unroll
    for (int r = 0; r < 4; ++r) t2a[r] = 0.f;

    const int posb3 = (ln < 16) ? ((ln / 4) * 32 + (ln % 4) * 2) : 144;
    const int pxt2 = (w - 4) * 16 + l16;   // valid for w>=4
    const int posbt2 = (w >= 4 && pxt2 < 49) ? ((pxt2 / 7 + 1) * 16 + (pxt2 % 7 + 1)) : 144;
    __syncthreads();

    for (int half = 0; half < 2; ++half) {
        const int ics = half * 64;
        for (int qq = tid; qq < 784; qq += 512) {
            int px = qq >> 4, ic4 = (qq & 15) * 4;
            float4 v = *(const float4*)&d2f[px * 128 + ics + ic4];
            float vv[4] = {v.x, v.y, v.z, v.w};
            ushort4 h4, l4; cvt4(vv, &h4, &l4);
            int pos = (px / 7 + 1) * 16 + (px % 7 + 1);
            *(ushort4*)&dhH[pos * 72 + ic4] = h4;
            *(ushort4*)&dhL[pos * 72 + ic4] = l4;
        }
        for (int qq = tid; qq < 1024; qq += 512) {
            int m = qq >> 6, k = qq & 63;
            float v = (m < 6) ? wt2[m * 128 + ics + k] : 0.f;
            unsigned short h = f2bf(v);
            t2H[m * 72 + k] = h;
            t2L[m * 72 + k] = f2bf(v - bf2f(h));
        }
        ushort4 pwh[4], pwl[4];
#pragma unroll
        for (int it = 0; it < 4; ++it) {
            int qq = tid + it * 512;
            int oc = qq >> 4, ic4 = (qq & 15) * 4;
            size_t gi = ((size_t)(0 * 128 + oc)) * C128 + ics + ic4;
            pwh[it] = *(const ushort4*)&w3h[gi];
            pwl[it] = *(const ushort4*)&w3l[gi];
        }
        __syncthreads();

        for (int tap = 0; tap < 9; ++tap) {
#pragma unroll
            for (int it = 0; it < 4; ++it) {
                int qq = tid + it * 512;
                int oc = qq >> 4, ic4 = (qq & 15) * 4;
                *(ushort4*)&w3H[oc * 72 + ic4] = pwh[it];
                *(ushort4*)&w3L[oc * 72 + ic4] = pwl[it];
            }
            if (tap < 8) {
#pragma unroll
                for (int it = 0; it < 4; ++it) {
                    int qq = tid + it * 512;
                    int oc = qq >> 4, ic4 = (qq & 15) * 4;
                    size_t gi = ((size_t)((tap + 1) * 128 + oc)) * C128 + ics + ic4;
                    pwh[it] = *(const ushort4*)&w3h[gi];
                    pwl[it] = *(const ushort4*)&w3l[gi];
                }
            }
            __syncthreads();
            const int off = (tap / 3) * 16 + (tap % 3);
            if (w < 4) {
#pragma unroll
                for (int c = 0; c < 4; ++c) {
                    const int ko = c * 16 + q * 8;
                    int pp = (posb3 + off) * 72 + ko;
                    frag8 aH = *(const frag8*)&dhH[pp];
                    frag8 aL = *(const frag8*)&dhL[pp];
                    int oc = w * 32 + ln;
                    frag8 bH = *(const frag8*)&w3H[oc * 72 + ko];
                    frag8 bL = *(const frag8*)&w3L[oc * 72 + ko];
                    c3 = __builtin_amdgcn_mfma_f32_32x32x16_bf16(aH, bH, c3, 0, 0, 0);
                    c3 = __builtin_amdgcn_mfma_f32_32x32x16_bf16(aH, bL, c3, 0, 0, 0);
                    c3 = __builtin_amdgcn_mfma_f32_32x32x16_bf16(aL, bH, c3, 0, 0, 0);
                }
            } else if (tap == 0) {
                // t2 on this half (dh is stable during the tap loop)
#pragma unroll
                for (int c = 0; c < 2; ++c) {
                    int ko = c * 32 + q4 * 8;
                    frag8 aH = *(const frag8*)&t2H[l16 * 72 + ko];
                    frag8 aL = *(const frag8*)&t2L[l16 * 72 + ko];
                    frag8 bH = *(const frag8*)&dhH[posbt2 * 72 + ko];
                    frag8 bL = *(const frag8*)&dhL[posbt2 * 72 + ko];
                    t2a = __builtin_amdgcn_mfma_f32_16x16x32_bf16(aH, bH, t2a, 0, 0, 0);
                    t2a = __builtin_amdgcn_mfma_f32_16x16x32_bf16(aH, bL, t2a, 0, 0, 0);
                    t2a = __builtin_amdgcn_mfma_f32_16x16x32_bf16(aL, bH, t2a, 0, 0, 0);
                }
            }
            __syncthreads();
        }
    }

    // conv3 epilogue -> d3f[oc][px]
    if (w < 4) {
        int oc = w * 32 + ln;
        float bias = b3[oc];
#pragma unroll
        for (int r = 0; r < 16; ++r) {
            int px = (r & 3) + 8 * (r >> 2) + 4 * q;
            if (px < 16) d3f[oc * 16 + px] = fmaxf(c3[r] + bias, 0.f);
        }
    } else {
        // t2 epilogue -> scores
#pragma unroll
        for (int r = 0; r < 4; ++r) {
            int oc = q4 * 4 + r;
            if (oc < 6 && pxt2 < 49) {
                float v = t2a[r] + bt2[oc];
                sbuf[1176 + oc * 49 + pxt2] = v;
                score_out[b * NA + 1176 + oc * 49 + pxt2] = v;
            }
        }
    }
    for (int i = tid; i < 1152; i += 512) wt3s[i] = wt3[i];
    __syncthreads();

    // ================= phase C: t3 (VALU) + anchor staging =================
    if (tid < 144) {
        int oc = tid >> 4, px = tid & 15;
        float s = bt3[oc];
        for (int ic = 0; ic < 128; ++ic) s += wt3s[oc * 128 + ic] * d3f[ic * 16 + px];
        sbuf[1470 + oc * 16 + px] = s;
        score_out[b * NA + 1470 + oc * 16 + px] = s;
    }
    for (int j = tid; j < NA; j += 512) {
        int4 a = ((const int4*)anchors)[j];
        float a0 = (float)a.x, a1 = (float)a.y, a2 = (float)a.z, a3 = (float)a.w;
        y0s[j] = a0; x0s[j] = a1; y1s[j] = a2; x1s[j] = a3;
        ars[j] = (a2 - a0) * (a3 - a1);
    }
    __syncthreads();

    // ================= phase D: greedy hard-NMS top-4 (shuffle reduce) =================
    for (int it = 0; it < TOPN; ++it) {
        float bv = -INFINITY; int bi = NA;
        for (int j = tid; j < NA; j += 512) {
            float v = sbuf[j];
            if (v > bv || (v == bv && j < bi)) { bv = v; bi = j; }
        }
#pragma unroll
        for (int d = 1; d < 64; d <<= 1) {
            float ov = __shfl_xor(bv, d, 64);
            int   oi = __shfl_xor(bi, d, 64);
            if (ov > bv || (ov == bv && oi < bi)) { bv = ov; bi = oi; }
        }
        if (l == 0) { rv[w] = bv; ri[w] = bi; }
        __syncthreads();
        if (tid == 0) {
            float V = rv[0]; int K = ri[0];
#pragma unroll
            for (int j = 1; j < 8; ++j) {
                float ov = rv[j]; int oi = ri[j];
                if (ov > V || (ov == V && oi < K)) { V = ov; K = oi; }
            }
            ri[8] = K;
            out_idx[b * TOPN + it] = (float)K;
            out_prob[b * TOPN + it] = V;
            idx_ws[b * TOPN + it] = K;
        }
        __syncthreads();
        int K = ri[8];
        float ky0 = y0s[K], kx0 = x0s[K], ky1 = y1s[K], kx1 = x1s[K], ka = ars[K];
        for (int j = tid; j < NA; j += 512) {
            float iy = fmaxf(fminf(y1s[j], ky1) - fmaxf(y0s[j], ky0), 0.f);
            float ix = fmaxf(fminf(x1s[j], kx1) - fmaxf(x0s[j], kx0), 0.f);
            float inter = iy * ix;
            float iou = inter / (ars[j] + ka - inter);
            if (iou >= 0.25f) sbuf[j] = -INFINITY;
        }
        __syncthreads();
    }
}

// ---------------- bilinear crop-resize ----------------
__global__ __launch_bounds__(256) void k_crop(const float* __restrict__ x,
                                              const int* __restrict__ anchors,
                                              const int* __restrict__ idx_ws,
                                              float* __restrict__ out) {
    int blk = blockIdx.x;
    int crop = blk / OUTS;
    int i = blk % OUTS;
    int j = threadIdx.x;
    if (j >= OUTS) return;
    int b = crop >> 2;
    int a = idx_ws[crop];
    int y0 = anchors[a * 4], x0 = anchors[a * 4 + 1];
    int y1 = anchors[a * 4 + 2], x1 = anchors[a * 4 + 3];

    float ti = (float)i / 223.f;
    float ys = (float)y0 + ti * (float)(y1 - y0 - 1);
    int yi0 = (int)ys;
    int yi1 = min(yi0 + 1, HP - 1);
    float wy = ys - (float)yi0;

    float tj = (float)j / 223.f;
    float xs = (float)x0 + tj * (float)(x1 - x0 - 1);
    int xi0 = (int)xs;
    int xi1 = min(xi0 + 1, HP - 1);
    float wx = xs - (float)xi0;

    int ry0 = yi0 - PADW, ry1 = yi1 - PADW, rx0 = xi0 - PADW, rx1 = xi1 - PADW;
    bool vy0 = (ry0 >= 0) && (ry0 < IM), vy1 = (ry1 >= 0) && (ry1 < IM);
    bool vx0 = (rx0 >= 0) && (rx0 < IM), vx1 = (rx1 >= 0) && (rx1 < IM);

    float w00 = (1.f - wy) * (1.f - wx), w01 = (1.f - wy) * wx;
    float w10 = wy * (1.f - wx), w11 = wy * wx;

#pragma unroll
    for (int c = 0; c < 3; ++c) {
        const float* xp = x + (size_t)(b * 3 + c) * IM * IM;
        float g00 = (vy0 && vx0) ? xp[ry0 * IM + rx0] : 0.f;
        float g01 = (vy0 && vx1) ? xp[ry0 * IM + rx1] : 0.f;
        float g10 = (vy1 && vx0) ? xp[ry1 * IM + rx0] : 0.f;
        float g11 = (vy1 && vx1) ? xp[ry1 * IM + rx1] : 0.f;
        out[(size_t)(crop * 3 + c) * OUTS * OUTS + i * OUTS + j] =
            g00 * w00 + g01 * w01 + g10 * w10 + g11 * w11;
    }
}

extern "C" void kernel_launch(void* const* d_in, const int* in_sizes, int n_in,
                              void* d_out, int out_size, void* d_ws, size_t ws_size,
                              hipStream_t stream) {
    (void)in_sizes; (void)n_in; (void)out_size; (void)ws_size;
    const float* x    = (const float*)d_in[0];
    const float* rpn  = (const float*)d_in[1];
    const float* w1   = (const float*)d_in[2];
    const float* b1   = (const float*)d_in[3];
    const float* w2   = (const float*)d_in[4];
    const float* b2   = (const float*)d_in[5];
    const float* w3   = (const float*)d_in[6];
    const float* b3   = (const float*)d_in[7];
    const float* wt1  = (const float*)d_in[8];
    const float* bt1  = (const float*)d_in[9];
    const float* wt2  = (const float*)d_in[10];
    const float* bt2  = (const float*)d_in[11];
    const float* wt3  = (const float*)d_in[12];
    const float* bt3  = (const float*)d_in[13];
    const int*   anc  = (const int*)d_in[14];

    float* out = (float*)d_out;
    float* ws  = (float*)d_ws;
    float* d1  = ws + WS_D1;
    int*   idxw = (int*)(ws + WS_IDX);
    unsigned short* w1h = (unsigned short*)(ws + WS_WT);
    unsigned short* w1l = w1h + NWT1;
    unsigned short* w2h = w1l + NWT1;
    unsigned short* w2l = w2h + NWT2;
    unsigned short* w3h = w2l + NWT2;
    unsigned short* w3l = w3h + NWT2;
    unsigned short* rpnTH = w3l + NWT2;
    unsigned short* rpnTL = rpnTH + NRPNT;

    static const int TAIL_LDS = 160568;
    hipFuncSetAttribute((const void*)k_tail, hipFuncAttributeMaxDynamicSharedMemorySize, TAIL_LDS);

    k_prep<<<3232, 256, 0, stream>>>(w1, w1h, w1l, w2, w2h, w2l, w3, w3h, w3l,
                                     rpn, rpnTH, rpnTL, b1, d1);
    k_conv1_mfma<<<256, 512, 0, stream>>>(rpnTH, rpnTL, w1h, w1l, d1);
    k_tail<<<BATCH, 512, TAIL_LDS, stream>>>(d1, w2h, w2l, w3h, w3l, b2, b3,
                                             wt1, bt1, wt2, bt2, wt3, bt3, anc,
                                             out + OFF_SCORE, out + OFF_TOPIDX,
                                             out + OFF_TOPPROB, idxw);
    k_crop<<<BATCH * TOPN * OUTS, 256, 0, stream>>>(x, anc, idxw, out);
}